// Round 5
// baseline (458.597 us; speedup 1.0000x reference)
//
#include <hip/hip_runtime.h>
#include <math.h>
#include <stdint.h>

typedef __bf16 bf16;
typedef __bf16 bf16x8 __attribute__((ext_vector_type(8)));
typedef __bf16 bf16x4 __attribute__((ext_vector_type(4)));
typedef float  floatx4 __attribute__((ext_vector_type(4)));

#define MFMA16(a, b, c) __builtin_amdgcn_mfma_f32_16x16x32_bf16(a, b, c, 0, 0, 0)
#define EXP2(x) __builtin_amdgcn_exp2f(x)

static constexpr int S  = 2048;
static constexpr int DM = 1024;
static constexpr int Dh = 64;
#define NEGBIG (-1e30f)
#define LOG2E  1.44269504088896340736f

// async global->LDS, 16B per lane; LDS dest = wave-uniform base + lane*16
__device__ __forceinline__ void gload16(const void* g, void* l) {
  __builtin_amdgcn_global_load_lds(
      (const __attribute__((address_space(1))) void*)(uintptr_t)g,
      (__attribute__((address_space(3))) void*)(uintptr_t)l,
      16, 0, 0);
}

// XOR-swizzled LDS offset for 64-elem (128B) rows, granule g (16B) xor'd by
// row&7 (attn tiles).
__device__ __forceinline__ int swz(int row, int g) {
  return row * 64 + ((g ^ (row & 7)) << 3);
}

// CU-load-balance remap for the attention grids: co-resident blocks on one
// CU have wgid stride 256 => same blockIdx.x (since 256 % 16 == 0) => same
// loop length nT=32-x => per-CU work spread 68..128 tile-iters (+-30%).
// Rotating x by (bh>>2) gives co-resident x in {x0,x0+4,x0+8,x0+12}:
// per-CU work 92..104 (+-6%). Bijective per bh.
__device__ __forceinline__ int xremap(int bx, int by) {
  return (bx + (by >> 2)) & 15;
}

// ---------------------------------------------------------------------------
// Pack queries|values|keys into one bf16 [8192][3072] buffer (X_all).
// ---------------------------------------------------------------------------
__global__ __launch_bounds__(256) void prep_convert(
    const float* __restrict__ q, const float* __restrict__ k,
    const float* __restrict__ v, bf16* __restrict__ X)
{
  int s = blockIdx.x;
  int c = threadIdx.x * 4;
  size_t src = (size_t)s * DM + c;
  float4 qv = *(const float4*)(q + src);
  float4 vv = *(const float4*)(v + src);
  float4 kv = *(const float4*)(k + src);
  size_t dst = (size_t)s * (3 * DM);
  bf16x4 t;
  t[0] = (bf16)qv.x; t[1] = (bf16)qv.y; t[2] = (bf16)qv.z; t[3] = (bf16)qv.w;
  *(bf16x4*)(X + dst + c) = t;
  t[0] = (bf16)vv.x; t[1] = (bf16)vv.y; t[2] = (bf16)vv.z; t[3] = (bf16)vv.w;
  *(bf16x4*)(X + dst + DM + c) = t;
  t[0] = (bf16)kv.x; t[1] = (bf16)kv.y; t[2] = (bf16)kv.z; t[3] = (bf16)kv.w;
  *(bf16x4*)(X + dst + 2 * DM + c) = t;
}

// ---------------------------------------------------------------------------
// Fold LoRA into effective weights (transposed bf16 for GEMM B-operand).
// ---------------------------------------------------------------------------
__global__ __launch_bounds__(256) void fold_weights(
    const float* __restrict__ Wq, const float* __restrict__ Aq, const float* __restrict__ Bq,
    const float* __restrict__ Wk, const float* __restrict__ Ak, const float* __restrict__ Bk,
    const float* __restrict__ Wv, const float* __restrict__ Av, const float* __restrict__ Bv,
    const float* __restrict__ Wo,
    bf16* __restrict__ WqT, bf16* __restrict__ WkT,
    bf16* __restrict__ WvT, bf16* __restrict__ WoT)
{
  __shared__ float tile[32][33];
  const int tx = threadIdx.x, ty = threadIdx.y;  // block (32, 8)
  const int n0 = blockIdx.x * 32, k0 = blockIdx.y * 32;
  for (int mi = 0; mi < 5; ++mi) {
    #pragma unroll
    for (int i = 0; i < 4; ++i) {
      int k = k0 + ty + i * 8, n = n0 + tx;
      float val = 0.f;
      if (mi == 0) {
        val = Wq[(size_t)k * DM + n];
        #pragma unroll
        for (int r = 0; r < 8; ++r) val += Aq[k * 8 + r] * Bq[(size_t)r * DM + n];
      } else if (mi == 1) {
        val = Wk[(size_t)k * DM + n];
        #pragma unroll
        for (int r = 0; r < 8; ++r) val += Ak[k * 8 + r] * Bk[(size_t)r * DM + n];
      } else if (mi == 2) {
        val = Wv[(size_t)k * DM + n];
      } else if (mi == 3) {
        #pragma unroll
        for (int r = 0; r < 8; ++r) val += Av[k * 8 + r] * Bv[(size_t)r * DM + n];
      } else {
        val = Wo[(size_t)k * DM + n];
      }
      tile[ty + i * 8][tx] = val;
    }
    __syncthreads();
    #pragma unroll
    for (int i = 0; i < 4; ++i) {
      int n = n0 + ty + i * 8, k = k0 + tx;
      float val = tile[tx][ty + i * 8];
      if (mi == 0)      WqT[(size_t)n * DM + k] = (bf16)val;
      else if (mi == 1) WkT[(size_t)n * DM + k] = (bf16)val;
      else if (mi == 2) WvT[(size_t)n * 2048 + k] = (bf16)val;
      else if (mi == 3) WvT[(size_t)n * 2048 + 1024 + k] = (bf16)val;
      else              WoT[(size_t)n * DM + k] = (bf16)val;
    }
    __syncthreads();
  }
}

__global__ __launch_bounds__(256) void fold_bias(
    const float* __restrict__ Wqb, const float* __restrict__ Aqb,
    const float* __restrict__ BqW, const float* __restrict__ Bqb,
    const float* __restrict__ Wkb, const float* __restrict__ Akb,
    const float* __restrict__ BkW, const float* __restrict__ Bkb,
    const float* __restrict__ Wvb, const float* __restrict__ Avb,
    const float* __restrict__ BvW, const float* __restrict__ Bvb,
    const float* __restrict__ Wob,
    float* __restrict__ bq, float* __restrict__ bk,
    float* __restrict__ bv, float* __restrict__ bo)
{
  int n = blockIdx.x * 256 + threadIdx.x;
  float aq = Wqb[n] + Bqb[n];
  float ak = Wkb[n] + Bkb[n];
  float av = Wvb[n] + Bvb[n];
  #pragma unroll
  for (int r = 0; r < 8; ++r) {
    aq += Aqb[r] * BqW[(size_t)r * DM + n];
    ak += Akb[r] * BkW[(size_t)r * DM + n];
    av += Avb[r] * BvW[(size_t)r * DM + n];
  }
  bq[n] = aq; bk[n] = ak; bv[n] = av; bo[n] = Wob[n];
}

// ---------------------------------------------------------------------------
// 128x128 bf16 MFMA GEMM, 512 threads / 8 waves (32x64 per wave),
// double-buffered global_load_lds prefetch (one barrier per K-step),
// source-pre-swizzled LDS staging (granule ^= (row>>1)&3) so b128 frag
// reads are ~conflict-free.
// mode 0: fp32 [M][N] (+col bias)
// mode 1: bf16 [bh][s][d] scatter (+col bias)     (Q/K)
// mode 3: bf16 [bh][d][s] scatter (+ROW bias)     (V computed transposed)
// ---------------------------------------------------------------------------
__global__ __launch_bounds__(512, 4) void gemm_bf16(
    const bf16* __restrict__ A, int lda,
    const bf16* __restrict__ BT, int ldb,
    const float* __restrict__ bias,
    int M, int N, int K, float oscale,
    float* __restrict__ outF, bf16* __restrict__ outB, int mode)
{
  __shared__ bf16 sA[2][128 * 32];
  __shared__ bf16 sB[2][128 * 32];
  const int tid = threadIdx.x;
  const int bm0 = blockIdx.y * 128, bn0 = blockIdx.x * 128;
  const int w = tid >> 6, lane = tid & 63, lrow = lane & 15, quad = lane >> 4;
  const int wm = (w >> 1) * 32, wn = (w & 1) * 64;

  // staging: thread t loads ONE 16B granule of A and B per K-step.
  const int srow = tid >> 2;                        // 0..127
  const int sg   = (tid & 3) ^ ((srow >> 1) & 3);   // pre-swizzled src granule
  const bf16* Ag = A  + (size_t)(bm0 + srow) * lda + sg * 8;
  const bf16* Bg = BT + (size_t)(bn0 + srow) * ldb + sg * 8;
  const int wb = w * 512;      // per-wave LDS base (elements; 1024 B/wave)

  // swizzled fragment element offsets (row r granule quad -> slot quad^((r>>1)&3))
  int aoff[2], boff[4];
  #pragma unroll
  for (int i = 0; i < 2; ++i) {
    int r = wm + i * 16 + lrow;
    aoff[i] = r * 32 + ((quad ^ ((r >> 1) & 3)) << 3);
  }
  #pragma unroll
  for (int j = 0; j < 4; ++j) {
    int r = wn + j * 16 + lrow;
    boff[j] = r * 32 + ((quad ^ ((r >> 1) & 3)) << 3);
  }

  floatx4 zero = {0.f, 0.f, 0.f, 0.f};
  floatx4 acc[2][4];
  #pragma unroll
  for (int i = 0; i < 2; ++i)
    #pragma unroll
    for (int j = 0; j < 4; ++j) acc[i][j] = zero;

  const int nk = K >> 5;
  // prologue: stage K-step 0 into buffer 0
  gload16(Ag, &sA[0][wb]);
  gload16(Bg, &sB[0][wb]);

  for (int t = 0; t < nk; ++t) {
    const int cur = t & 1;
    __syncthreads();                       // drains staging of buf[cur]
    if (t + 1 < nk) {                      // prefetch next step into other half
      gload16(Ag + (size_t)(t + 1) * 32, &sA[cur ^ 1][wb]);
      gload16(Bg + (size_t)(t + 1) * 32, &sB[cur ^ 1][wb]);
    }
    bf16x8 aF[2], bF[4];
    #pragma unroll
    for (int i = 0; i < 2; ++i) aF[i] = *(const bf16x8*)&sA[cur][aoff[i]];
    #pragma unroll
    for (int j = 0; j < 4; ++j) bF[j] = *(const bf16x8*)&sB[cur][boff[j]];
    #pragma unroll
    for (int i = 0; i < 2; ++i)
      #pragma unroll
      for (int j = 0; j < 4; ++j)
        acc[i][j] = MFMA16(aF[i], bF[j], acc[i][j]);
  }

  if (mode == 3) {                       // row bias, [bh][d][s] coalesced
    #pragma unroll
    for (int i = 0; i < 2; ++i) {
      #pragma unroll
      for (int r = 0; r < 4; ++r) {
        int gm = bm0 + wm + i * 16 + quad * 4 + r;   // (h,d)
        float bvr = bias[gm];
        int h = gm >> 6, d = gm & 63;
        #pragma unroll
        for (int j = 0; j < 4; ++j) {
          int gn = bn0 + wn + j * 16 + lrow;          // (b,s)
          int b = gn >> 11, s = gn & 2047;
          outB[((size_t)(b * 16 + h) * 64 + d) * 2048 + s] =
              (bf16)(acc[i][j][r] + bvr);
        }
      }
    }
    return;
  }

  float bvs[4];
  #pragma unroll
  for (int j = 0; j < 4; ++j) bvs[j] = bias[bn0 + wn + j * 16 + lrow];

  #pragma unroll
  for (int i = 0; i < 2; ++i) {
    #pragma unroll
    for (int j = 0; j < 4; ++j) {
      #pragma unroll
      for (int r = 0; r < 4; ++r) {
        int gm = bm0 + wm + i * 16 + quad * 4 + r;
        int gn = bn0 + wn + j * 16 + lrow;
        float v = (acc[i][j][r] + bvs[j]) * oscale;
        if (mode == 0) {
          outF[(size_t)gm * N + gn] = v;
        } else {
          int b = gm >> 11, s = gm & 2047, h = gn >> 6, d = gn & 63;
          outB[((size_t)(b * 16 + h) * 2048 + s) * 64 + d] = (bf16)v;
        }
      }
    }
  }
}

// ---------------------------------------------------------------------------
// Pass 1 (log2 domain; Q pre-scaled by log2e): per-column stats over q>=c.
// Emits C[c] = m + 3 + log2(sum); pass2 weight = exp2(s - C).
// ---------------------------------------------------------------------------
__global__ __launch_bounds__(256) void attn_pass1(
    const bf16* __restrict__ Qb, const bf16* __restrict__ Kb,
    float* __restrict__ statC)
{
  const int bh = blockIdx.y;
  const int x = xremap(blockIdx.x, blockIdx.y);   // 0..15, CU-load balanced
  const int q0a = x * 64, q0b = (31 - x) * 64;
  const int tid = threadIdx.x;
  const int w = tid >> 6, lane = tid & 63, lrow = lane & 15, quad = lane >> 4;
  const bf16* Qh = Qb + (size_t)bh * S * Dh;
  const bf16* Kh = Kb + (size_t)bh * S * Dh;

  int cbase[8];
  #pragma unroll
  for (int cf = 0; cf < 8; ++cf)
    cbase[cf] = (cf < 4) ? (q0a + cf * 16) : (q0b + (cf - 4) * 16);

  bf16x8 kf[8][2];
  #pragma unroll
  for (int cf = 0; cf < 8; ++cf) {
    const bf16* kp = Kh + (size_t)(cbase[cf] + lrow) * Dh + quad * 8;
    kf[cf][0] = *(const bf16x8*)kp;
    kf[cf][1] = *(const bf16x8*)(kp + 32);
  }

  float rm[8], rs[8];
  #pragma unroll
  for (int cf = 0; cf < 8; ++cf) { rm[cf] = NEGBIG; rs[cf] = 0.f; }

  const int qs = q0a + w * 16;
  const bf16* qp0 = Qh + (size_t)(qs + lrow) * Dh + quad * 8;
  bf16x8 a0 = *(const bf16x8*)qp0, a1 = *(const bf16x8*)(qp0 + 32);

  for (int q0 = qs; q0 < S; q0 += 64) {
    bf16x8 n0 = a0, n1 = a1;
    if (q0 + 64 < S) {
      const bf16* np = Qh + (size_t)(q0 + 64 + lrow) * Dh + quad * 8;
      n0 = *(const bf16x8*)np; n1 = *(const bf16x8*)(np + 32);
    }
    #pragma unroll
    for (int cf = 0; cf < 8; ++cf) {
      const int c0f = cbase[cf];
      if (c0f > q0 + 15) continue;          // frag fully masked (uniform)
      floatx4 sacc = {0.f, 0.f, 0.f, 0.f};
      sacc = MFMA16(a0, kf[cf][0], sacc);
      sacc = MFMA16(a1, kf[cf][1], sacc);
      float v0 = sacc[0], v1 = sacc[1], v2 = sacc[2], v3 = sacc[3];
      if (q0 < c0f + 15) {                  // partially masked frag
        int c = c0f + lrow, qb = q0 + quad * 4;
        v0 = (qb + 0 >= c) ? v0 : NEGBIG;
        v1 = (qb + 1 >= c) ? v1 : NEGBIG;
        v2 = (qb + 2 >= c) ? v2 : NEGBIG;
        v3 = (qb + 3 >= c) ? v3 : NEGBIG;
      }
      float mt = fmaxf(fmaxf(v0, v1), fmaxf(v2, v3));
      float nm = fmaxf(rm[cf], mt);
      rs[cf] = rs[cf] * EXP2(rm[cf] - nm)
             + EXP2(v0 - nm) + EXP2(v1 - nm)
             + EXP2(v2 - nm) + EXP2(v3 - nm);
      rm[cf] = nm;
    }
    a0 = n0; a1 = n1;
  }

  #pragma unroll
  for (int cf = 0; cf < 8; ++cf) {
    #pragma unroll
    for (int off = 16; off < 64; off <<= 1) {
      float om = __shfl_xor(rm[cf], off, 64);
      float os = __shfl_xor(rs[cf], off, 64);
      float nm = fmaxf(rm[cf], om);
      rs[cf] = rs[cf] * EXP2(rm[cf] - nm) + os * EXP2(om - nm);
      rm[cf] = nm;
    }
  }

  __shared__ float smm[4][128];
  __shared__ float sms[4][128];
  if (quad == 0) {
    #pragma unroll
    for (int cf = 0; cf < 8; ++cf) {
      smm[w][cf * 16 + lrow] = rm[cf];
      sms[w][cf * 16 + lrow] = rs[cf];
    }
  }
  __syncthreads();
  if (tid < 128) {
    float m = smm[0][tid], sum = sms[0][tid];
    #pragma unroll
    for (int ww = 1; ww < 4; ++ww) {
      float om = smm[ww][tid], os = sms[ww][tid];
      float nm = fmaxf(m, om);
      sum = sum * EXP2(m - nm) + os * EXP2(om - nm);
      m = nm;
    }
    int col = (tid < 64) ? (q0a + tid) : (q0b + tid - 64);
    statC[(size_t)bh * S + col] = m + 3.0f + __log2f(sum);
  }
}

// ---------------------------------------------------------------------------
// Pass 2: out[q,:] = sum_{k<=q} exp2(s[q,k] - C[k]) * V[k,:]
// 256 threads / 4 waves, each wave owns TWO 16-row strips (mi=0,1) — the
// two independent strips give intra-wave ILP that hides MFMA/exp latency;
// 512-thread variants (R2: spilled; R3: lost co-residency, less ILP) were
// 301/111 µs vs this structure's 81.5 µs. Do not split strips across waves.
// blockIdx.x remapped via xremap so co-resident blocks on a CU carry
// different loop lengths (per-CU work +-6% instead of +-30%).
// S^T orientation: QK MFMA as (kf, qf) -> lane holds col=q, rows=4
// consecutive key-cols -> P written as ONE ds_write_b64 per frag.
// All LDS XOR-swizzled (128B rows) -> conflict-free.
// ---------------------------------------------------------------------------
__global__ __launch_bounds__(256) void attn_pass2(
    const bf16* __restrict__ Qb, const bf16* __restrict__ Kb,
    const bf16* __restrict__ Vt, const float* __restrict__ statC,
    bf16* __restrict__ AttOut)
{
  const int bh = blockIdx.y;
  const int x = xremap(blockIdx.x, blockIdx.y);   // 0..15, CU-load balanced
  const int q0a = x * 64, q0b = (31 - x) * 64;
  const int tid = threadIdx.x;
  const int w = tid >> 6, lane = tid & 63, lrow = lane & 15, quad = lane >> 4;
  const bf16* Qh = Qb + (size_t)bh * S * Dh;
  const bf16* Kh = Kb + (size_t)bh * S * Dh;
  const bf16* Vh = Vt + (size_t)bh * Dh * S;   // [d][s]
  const float* sth = statC + (size_t)bh * S;

  __shared__ bf16 sK[64 * 64];         // [s-row][d], swizzled 128B rows
  __shared__ bf16 sV[64 * 64];         // [d-row][s], swizzled
  __shared__ bf16 pbuf[4][32 * 64];    // per-wave P [q-row][c], swizzled

  const int r0m[2] = { q0a + w * 16, q0b + w * 16 };
  bf16x8 qf[2][2];
  #pragma unroll
  for (int mi = 0; mi < 2; ++mi) {
    const bf16* qp = Qh + (size_t)(r0m[mi] + lrow) * Dh + quad * 8;
    qf[mi][0] = *(const bf16x8*)qp;
    qf[mi][1] = *(const bf16x8*)(qp + 32);
  }

  floatx4 zero = {0.f, 0.f, 0.f, 0.f};
  floatx4 accO[2][4];
  #pragma unroll
  for (int mi = 0; mi < 2; ++mi)
    #pragma unroll
    for (int nf = 0; nf < 4; ++nf) accO[mi][nf] = zero;

  const int sr = tid >> 3;        // 0..31
  const int g  = tid & 7;         // 16B granule
  const int nT = 32 - x;          // tiles of 64 cols
  bf16* const pw = &pbuf[w][0];

  // prefetch tile 0 (K, V)
  bf16x8 kg0 = *(const bf16x8*)(Kh + (size_t)sr * Dh + g * 8);
  bf16x8 kg1 = *(const bf16x8*)(Kh + (size_t)(sr + 32) * Dh + g * 8);
  bf16x8 vg0 = *(const bf16x8*)(Vh + (size_t)sr * S + g * 8);
  bf16x8 vg1 = *(const bf16x8*)(Vh + (size_t)(sr + 32) * S + g * 8);

  for (int kt = 0; kt < nT; ++kt) {
    const int kc = kt * 64;
    __syncthreads();
    *(bf16x8*)&sK[swz(sr, g)]      = kg0;
    *(bf16x8*)&sK[swz(sr + 32, g)] = kg1;
    *(bf16x8*)&sV[swz(sr, g)]      = vg0;
    *(bf16x8*)&sV[swz(sr + 32, g)] = vg1;
    // C constants for this tile: quad-uniform float4 per cf (VMEM, L1-served)
    float4 c4[4];
    #pragma unroll
    for (int cf = 0; cf < 4; ++cf)
      c4[cf] = *(const float4*)&sth[kc + cf * 16 + quad * 4];
    __syncthreads();
    if (kt + 1 < nT) {                     // prefetch next K/V tile
      const int kn = kc + 64;
      kg0 = *(const bf16x8*)(Kh + (size_t)(kn + sr) * Dh + g * 8);
      kg1 = *(const bf16x8*)(Kh + (size_t)(kn + sr + 32) * Dh + g * 8);
      vg0 = *(const bf16x8*)(Vh + (size_t)sr * S + kn + g * 8);
      vg1 = *(const bf16x8*)(Vh + (size_t)(sr + 32) * S + kn + g * 8);
    }

    bool actH[2][2];
    #pragma unroll
    for (int mi = 0; mi < 2; ++mi) {
      actH[mi][0] = kc      <= r0m[mi] + 15;
      actH[mi][1] = kc + 32 <= r0m[mi] + 15;
    }

    // ---- S^T = K·Q^T + exp2 phase (cols=q, rows=c) ----
    #pragma unroll
    for (int cf = 0; cf < 4; ++cf) {
      const int hh = cf >> 1;
      if (!actH[0][hh] && !actH[1][hh]) continue;
      const int c0f = kc + cf * 16;
      const int cl = cf * 16;
      bf16x8 kf0 = *(const bf16x8*)&sK[swz(cl + lrow, quad)];
      bf16x8 kf1 = *(const bf16x8*)&sK[swz(cl + lrow, 4 + quad)];
      const float* cc = &c4[cf].x;                 // C[c0f+quad*4+r]
      const int crb = c0f + quad * 4;              // this lane's row base (c)
      #pragma unroll
      for (int mi = 0; mi < 2; ++mi) {
        if (!actH[mi][hh]) continue;
        const int r0 = r0m[mi];
        // dest: row mi*16+lrow, cols cf*16+quad*4..+3 -> one b64
        const int gq = cf * 2 + (quad >> 1);
        const int poff = (mi * 16 + lrow) * 64 +
                         ((gq ^ (lrow & 7)) << 3) + (quad & 1) * 4;
        bf16x4 pk;
        if (c0f > r0 + 15) {               // fully masked frag
          pk[0] = pk[1] = pk[2] = pk[3] = (bf16)0.f;
        } else {
          floatx4 sacc = zero;
          sacc = MFMA16(kf0, qf[mi][0], sacc);     // A=K -> row=c, col=q
          sacc = MFMA16(kf1, qf[mi][1], sacc);
          const bool fullf = (c0f + 15 <= r0);
          const int qlane = r0 + lrow;
          #pragma unroll
          for (int r = 0; r < 4; ++r) {
            float p = EXP2(sacc[r] - cc[r]);
            if (!fullf) p = (crb + r <= qlane) ? p : 0.f;
            pk[r] = (bf16)p;
          }
        }
        *(bf16x4*)(pw + poff) = pk;
      }
    }

    // ---- PV phase (two K=32 halves) ----
    #pragma unroll
    for (int hh = 0; hh < 2; ++hh) {
      if (!actH[0][hh] && !actH[1][hh]) continue;
      bf16x8 vf[4];
      #pragma unroll
      for (int nf = 0; nf < 4; ++nf)
        vf[nf] = *(const bf16x8*)&sV[swz(nf * 16 + lrow, hh * 4 + quad)];
      #pragma unroll
      for (int mi = 0; mi < 2; ++mi) {
        if (!actH[mi][hh]) continue;
        bf16x8 pf = *(const bf16x8*)(pw + swz(mi * 16 + lrow, hh * 4 + quad));
        #pragma unroll
        for (int nf = 0; nf < 4; ++nf)
          accO[mi][nf] = MFMA16(pf, vf[nf], accO[mi][nf]);
      }
    }
  }

  const int b = bh >> 4, h = bh & 15;
  #pragma unroll
  for (int mi = 0; mi < 2; ++mi) {
    #pragma unroll
    for (int nf = 0; nf < 4; ++nf) {
      #pragma unroll
      for (int r = 0; r < 4; ++r) {
        int qq = r0m[mi] + quad * 4 + r;
        int d = nf * 16 + lrow;
        AttOut[((size_t)(b * S + qq)) * DM + h * 64 + d] = (bf16)accO[mi][nf][r];
      }
    }
  }
}

// ---------------------------------------------------------------------------
extern "C" void kernel_launch(void* const* d_in, const int* in_sizes, int n_in,
                              void* d_out, int out_size, void* d_ws, size_t ws_size,
                              hipStream_t stream) {
  (void)in_sizes; (void)n_in; (void)out_size; (void)ws_size;
  const float* queries = (const float*)d_in[0];
  const float* keys    = (const float*)d_in[1];
  const float* values  = (const float*)d_in[2];
  const float* Wq_w = (const float*)d_in[3];  const float* Wq_b = (const float*)d_in[4];
  const float* Wk_w = (const float*)d_in[5];  const float* Wk_b = (const float*)d_in[6];
  const float* Wv_w = (const float*)d_in[7];  const float* Wv_b = (const float*)d_in[8];
  const float* Aq_w = (const float*)d_in[9];  const float* Aq_b = (const float*)d_in[10];
  const float* Bq_w = (const float*)d_in[11]; const float* Bq_b = (const float*)d_in[12];
  const float* Ak_w = (const float*)d_in[13]; const float* Ak_b = (const float*)d_in[14];
  const float* Bk_w = (const float*)d_in[15]; const float* Bk_b = (const float*)d_in[16];
  const float* Av_w = (const float*)d_in[17]; const float* Av_b = (const float*)d_in[18];
  const float* Bv_w = (const float*)d_in[19]; const float* Bv_b = (const float*)d_in[20];
  const float* Wo_w = (const float*)d_in[21]; const float* Wo_b = (const float*)d_in[22];
  float* out = (float*)d_out;

  char* ws = (char*)d_ws;
  size_t off = 0;
  auto alloc = [&](size_t bytes) -> void* {
    void* p = ws + off;
    off += (bytes + 255) & ~(size_t)255;
    return p;
  };
  bf16*  X_all  = (bf16*)alloc((size_t)8192 * 3072 * 2);
  bf16*  Qb     = (bf16*)alloc((size_t)64 * 2048 * 64 * 2);
  bf16*  Kb     = (bf16*)alloc((size_t)64 * 2048 * 64 * 2);
  bf16*  Vt     = (bf16*)alloc((size_t)64 * 64 * 2048 * 2);
  bf16*  AttOut = (bf16*)alloc((size_t)8192 * 1024 * 2);
  bf16*  WqT    = (bf16*)alloc((size_t)1024 * 1024 * 2);
  bf16*  WkT    = (bf16*)alloc((size_t)1024 * 1024 * 2);
  bf16*  WvT    = (bf16*)alloc((size_t)1024 * 2048 * 2);
  bf16*  WoT    = (bf16*)alloc((size_t)1024 * 1024 * 2);
  float* bq     = (float*)alloc(1024 * 4);
  float* bk     = (float*)alloc(1024 * 4);
  float* bv     = (float*)alloc(1024 * 4);
  float* bo     = (float*)alloc(1024 * 4);
  float* statC  = (float*)alloc((size_t)64 * 2048 * 4);

  prep_convert<<<8192, 256, 0, stream>>>(queries, keys, values, X_all);
  fold_weights<<<dim3(32, 32), dim3(32, 8), 0, stream>>>(
      Wq_w, Aq_w, Bq_w, Wk_w, Ak_w, Bk_w, Wv_w, Av_w, Bv_w, Wo_w,
      WqT, WkT, WvT, WoT);
  fold_bias<<<4, 256, 0, stream>>>(
      Wq_b, Aq_b, Bq_w, Bq_b, Wk_b, Ak_b, Bk_w, Bk_b,
      Wv_b, Av_b, Bv_w, Bv_b, Wo_b, bq, bk, bv, bo);

  // Q gets log2e folded in (scores in log2 domain -> exp2-only softmax)
  gemm_bf16<<<dim3(8, 64), 512, 0, stream>>>(X_all,        3072, WqT, 1024, bq, 8192, 1024, 1024, LOG2E, nullptr, Qb, 1);
  gemm_bf16<<<dim3(8, 64), 512, 0, stream>>>(X_all + 2048, 3072, WkT, 1024, bk, 8192, 1024, 1024, 1.0f,  nullptr, Kb, 1);
  // V computed TRANSPOSED: Vt = WvT @ X^T  (M=1024 rows=(h,d), N=8192=(b,s))
  gemm_bf16<<<dim3(64, 8), 512, 0, stream>>>(WvT, 2048, X_all + 1024, 3072, bv, 1024, 8192, 2048, 1.0f, nullptr, Vt, 3);

  attn_pass1<<<dim3(16, 64), 256, 0, stream>>>(Qb, Kb, statC);
  attn_pass2<<<dim3(16, 64), 256, 0, stream>>>(Qb, Kb, Vt, statC, AttOut);

  gemm_bf16<<<dim3(8, 64), 512, 0, stream>>>(AttOut, 1024, WoT, 1024, bo, 8192, 1024, 1024, 1.0f, out, nullptr, 0);
}

// Round 6
// 441.764 us; speedup vs baseline: 1.0381x; 1.0381x over previous
//
#include <hip/hip_runtime.h>
#include <math.h>
#include <stdint.h>

typedef __bf16 bf16;
typedef __bf16 bf16x8 __attribute__((ext_vector_type(8)));
typedef __bf16 bf16x4 __attribute__((ext_vector_type(4)));
typedef float  floatx4 __attribute__((ext_vector_type(4)));

#define MFMA16(a, b, c) __builtin_amdgcn_mfma_f32_16x16x32_bf16(a, b, c, 0, 0, 0)
#define EXP2(x) __builtin_amdgcn_exp2f(x)

static constexpr int S  = 2048;
static constexpr int DM = 1024;
static constexpr int Dh = 64;
static constexpr size_t QBSZ = (size_t)64 * 2048 * 64;   // elems in Qb (Kb follows)
#define NEGBIG (-1e30f)
#define LOG2E  1.44269504088896340736f

// async global->LDS, 16B per lane; LDS dest = wave-uniform base + lane*16
__device__ __forceinline__ void gload16(const void* g, void* l) {
  __builtin_amdgcn_global_load_lds(
      (const __attribute__((address_space(1))) void*)(uintptr_t)g,
      (__attribute__((address_space(3))) void*)(uintptr_t)l,
      16, 0, 0);
}

// XOR-swizzled LDS offset for 64-elem (128B) rows, granule g (16B) xor'd by
// row&7 (attn tiles).
__device__ __forceinline__ int swz(int row, int g) {
  return row * 64 + ((g ^ (row & 7)) << 3);
}

// ---------------------------------------------------------------------------
// Pack queries|values|keys into one bf16 [8192][3072] buffer (X_all).
// ---------------------------------------------------------------------------
__global__ __launch_bounds__(256) void prep_convert(
    const float* __restrict__ q, const float* __restrict__ k,
    const float* __restrict__ v, bf16* __restrict__ X)
{
  int s = blockIdx.x;
  int c = threadIdx.x * 4;
  size_t src = (size_t)s * DM + c;
  float4 qv = *(const float4*)(q + src);
  float4 vv = *(const float4*)(v + src);
  float4 kv = *(const float4*)(k + src);
  size_t dst = (size_t)s * (3 * DM);
  bf16x4 t;
  t[0] = (bf16)qv.x; t[1] = (bf16)qv.y; t[2] = (bf16)qv.z; t[3] = (bf16)qv.w;
  *(bf16x4*)(X + dst + c) = t;
  t[0] = (bf16)vv.x; t[1] = (bf16)vv.y; t[2] = (bf16)vv.z; t[3] = (bf16)vv.w;
  *(bf16x4*)(X + dst + DM + c) = t;
  t[0] = (bf16)kv.x; t[1] = (bf16)kv.y; t[2] = (bf16)kv.z; t[3] = (bf16)kv.w;
  *(bf16x4*)(X + dst + 2 * DM + c) = t;
}

// ---------------------------------------------------------------------------
// Fold LoRA into effective weights (transposed bf16 for GEMM B-operand).
// Wq gets LOG2E folded in (so the merged Q|K GEMM uses one oscale=1).
// ---------------------------------------------------------------------------
__global__ __launch_bounds__(256) void fold_weights(
    const float* __restrict__ Wq, const float* __restrict__ Aq, const float* __restrict__ Bq,
    const float* __restrict__ Wk, const float* __restrict__ Ak, const float* __restrict__ Bk,
    const float* __restrict__ Wv, const float* __restrict__ Av, const float* __restrict__ Bv,
    const float* __restrict__ Wo,
    bf16* __restrict__ WqT, bf16* __restrict__ WkT,
    bf16* __restrict__ WvT, bf16* __restrict__ WoT)
{
  __shared__ float tile[32][33];
  const int tx = threadIdx.x, ty = threadIdx.y;  // block (32, 8)
  const int n0 = blockIdx.x * 32, k0 = blockIdx.y * 32;
  for (int mi = 0; mi < 5; ++mi) {
    #pragma unroll
    for (int i = 0; i < 4; ++i) {
      int k = k0 + ty + i * 8, n = n0 + tx;
      float val = 0.f;
      if (mi == 0) {
        val = Wq[(size_t)k * DM + n];
        #pragma unroll
        for (int r = 0; r < 8; ++r) val += Aq[k * 8 + r] * Bq[(size_t)r * DM + n];
        val *= LOG2E;
      } else if (mi == 1) {
        val = Wk[(size_t)k * DM + n];
        #pragma unroll
        for (int r = 0; r < 8; ++r) val += Ak[k * 8 + r] * Bk[(size_t)r * DM + n];
      } else if (mi == 2) {
        val = Wv[(size_t)k * DM + n];
      } else if (mi == 3) {
        #pragma unroll
        for (int r = 0; r < 8; ++r) val += Av[k * 8 + r] * Bv[(size_t)r * DM + n];
      } else {
        val = Wo[(size_t)k * DM + n];
      }
      tile[ty + i * 8][tx] = val;
    }
    __syncthreads();
    #pragma unroll
    for (int i = 0; i < 4; ++i) {
      int n = n0 + ty + i * 8, k = k0 + tx;
      float val = tile[tx][ty + i * 8];
      if (mi == 0)      WqT[(size_t)n * DM + k] = (bf16)val;
      else if (mi == 1) WkT[(size_t)n * DM + k] = (bf16)val;
      else if (mi == 2) WvT[(size_t)n * 2048 + k] = (bf16)val;
      else if (mi == 3) WvT[(size_t)n * 2048 + 1024 + k] = (bf16)val;
      else              WoT[(size_t)n * DM + k] = (bf16)val;
    }
    __syncthreads();
  }
}

__global__ __launch_bounds__(256) void fold_bias(
    const float* __restrict__ Wqb, const float* __restrict__ Aqb,
    const float* __restrict__ BqW, const float* __restrict__ Bqb,
    const float* __restrict__ Wkb, const float* __restrict__ Akb,
    const float* __restrict__ BkW, const float* __restrict__ Bkb,
    const float* __restrict__ Wvb, const float* __restrict__ Avb,
    const float* __restrict__ BvW, const float* __restrict__ Bvb,
    const float* __restrict__ Wob,
    float* __restrict__ bq, float* __restrict__ bk,
    float* __restrict__ bv, float* __restrict__ bo)
{
  int n = blockIdx.x * 256 + threadIdx.x;
  float aq = Wqb[n] + Bqb[n];
  float ak = Wkb[n] + Bkb[n];
  float av = Wvb[n] + Bvb[n];
  #pragma unroll
  for (int r = 0; r < 8; ++r) {
    aq += Aqb[r] * BqW[(size_t)r * DM + n];
    ak += Akb[r] * BkW[(size_t)r * DM + n];
    av += Avb[r] * BvW[(size_t)r * DM + n];
  }
  bq[n] = aq * LOG2E;            // LOG2E folded (merged Q|K GEMM, oscale=1)
  bk[n] = ak; bv[n] = av; bo[n] = Wob[n];
}

// ---------------------------------------------------------------------------
// 128x128 bf16 MFMA GEMM, 512 threads / 8 waves (32x64 per wave),
// double-buffered global_load_lds prefetch (one barrier per K-step),
// source-pre-swizzled LDS staging (granule ^= (row>>1)&3) so b128 frag
// reads are ~conflict-free.
// mode 0: fp32 [M][N] (+col bias)
// mode 1: MERGED Q|K: N=2048, cols [0,1024) from X queries-cols -> Qb,
//         cols [1024,2048) from X keys-cols (A += 2048) -> Kb (=Qb+QBSZ).
//         bf16 [bh][s][d] scatter (+col bias).
// mode 3: bf16 [bh][d][s] scatter (+ROW bias)     (V computed transposed)
// ---------------------------------------------------------------------------
__global__ __launch_bounds__(512, 4) void gemm_bf16(
    const bf16* __restrict__ A, int lda,
    const bf16* __restrict__ BT, int ldb,
    const float* __restrict__ bias,
    int M, int N, int K, float oscale,
    float* __restrict__ outF, bf16* __restrict__ outB, int mode)
{
  __shared__ bf16 sA[2][128 * 32];
  __shared__ bf16 sB[2][128 * 32];
  const int tid = threadIdx.x;
  const int bm0 = blockIdx.y * 128, bn0 = blockIdx.x * 128;
  const int w = tid >> 6, lane = tid & 63, lrow = lane & 15, quad = lane >> 4;
  const int wm = (w >> 1) * 32, wn = (w & 1) * 64;

  // merged Q|K: n-blocks in the upper half read the keys columns of X_all
  const bf16* Abase = (mode == 1) ? (A + (size_t)(bn0 >> 10) * 2048) : A;

  // staging: thread t loads ONE 16B granule of A and B per K-step.
  const int srow = tid >> 2;                        // 0..127
  const int sg   = (tid & 3) ^ ((srow >> 1) & 3);   // pre-swizzled src granule
  const bf16* Ag = Abase + (size_t)(bm0 + srow) * lda + sg * 8;
  const bf16* Bg = BT + (size_t)(bn0 + srow) * ldb + sg * 8;
  const int wb = w * 512;      // per-wave LDS base (elements; 1024 B/wave)

  // swizzled fragment element offsets (row r granule quad -> slot quad^((r>>1)&3))
  int aoff[2], boff[4];
  #pragma unroll
  for (int i = 0; i < 2; ++i) {
    int r = wm + i * 16 + lrow;
    aoff[i] = r * 32 + ((quad ^ ((r >> 1) & 3)) << 3);
  }
  #pragma unroll
  for (int j = 0; j < 4; ++j) {
    int r = wn + j * 16 + lrow;
    boff[j] = r * 32 + ((quad ^ ((r >> 1) & 3)) << 3);
  }

  floatx4 zero = {0.f, 0.f, 0.f, 0.f};
  floatx4 acc[2][4];
  #pragma unroll
  for (int i = 0; i < 2; ++i)
    #pragma unroll
    for (int j = 0; j < 4; ++j) acc[i][j] = zero;

  const int nk = K >> 5;
  // prologue: stage K-step 0 into buffer 0
  gload16(Ag, &sA[0][wb]);
  gload16(Bg, &sB[0][wb]);

  for (int t = 0; t < nk; ++t) {
    const int cur = t & 1;
    __syncthreads();                       // drains staging of buf[cur]
    if (t + 1 < nk) {                      // prefetch next step into other half
      gload16(Ag + (size_t)(t + 1) * 32, &sA[cur ^ 1][wb]);
      gload16(Bg + (size_t)(t + 1) * 32, &sB[cur ^ 1][wb]);
    }
    bf16x8 aF[2], bF[4];
    #pragma unroll
    for (int i = 0; i < 2; ++i) aF[i] = *(const bf16x8*)&sA[cur][aoff[i]];
    #pragma unroll
    for (int j = 0; j < 4; ++j) bF[j] = *(const bf16x8*)&sB[cur][boff[j]];
    #pragma unroll
    for (int i = 0; i < 2; ++i)
      #pragma unroll
      for (int j = 0; j < 4; ++j)
        acc[i][j] = MFMA16(aF[i], bF[j], acc[i][j]);
  }

  if (mode == 3) {                       // row bias, [bh][d][s] coalesced
    #pragma unroll
    for (int i = 0; i < 2; ++i) {
      #pragma unroll
      for (int r = 0; r < 4; ++r) {
        int gm = bm0 + wm + i * 16 + quad * 4 + r;   // (h,d)
        float bvr = bias[gm];
        int h = gm >> 6, d = gm & 63;
        #pragma unroll
        for (int j = 0; j < 4; ++j) {
          int gn = bn0 + wn + j * 16 + lrow;          // (b,s)
          int b = gn >> 11, s = gn & 2047;
          outB[((size_t)(b * 16 + h) * 64 + d) * 2048 + s] =
              (bf16)(acc[i][j][r] + bvr);
        }
      }
    }
    return;
  }

  float bvs[4];
  #pragma unroll
  for (int j = 0; j < 4; ++j) bvs[j] = bias[bn0 + wn + j * 16 + lrow];

  #pragma unroll
  for (int i = 0; i < 2; ++i) {
    #pragma unroll
    for (int j = 0; j < 4; ++j) {
      #pragma unroll
      for (int r = 0; r < 4; ++r) {
        int gm = bm0 + wm + i * 16 + quad * 4 + r;
        int gn = bn0 + wn + j * 16 + lrow;
        float v = (acc[i][j][r] + bvs[j]) * oscale;
        if (mode == 0) {
          outF[(size_t)gm * N + gn] = v;
        } else {
          // merged Q|K scatter: part 0 -> Qb, part 1 -> Kb (contiguous)
          int b = gm >> 11, s = gm & 2047;
          int part = gn >> 10, h = (gn >> 6) & 15, d = gn & 63;
          outB[(size_t)part * QBSZ +
               ((size_t)(b * 16 + h) * 2048 + s) * 64 + d] = (bf16)v;
        }
      }
    }
  }
}

// ---------------------------------------------------------------------------
// Pass 1 (log2 domain; Q pre-scaled by log2e): per-column stats over q>=c.
// Emits C[c] = m + 3 + log2(sum); pass2 weight = exp2(s - C).
// NOTE: x = blockIdx.x directly. R5's xremap "balance" regressed 35%:
// dispatch time is set by the x=0 long blocks, which lose co-resident
// company (and thus latency hiding) when mixed with short blocks.
// ---------------------------------------------------------------------------
__global__ __launch_bounds__(256) void attn_pass1(
    const bf16* __restrict__ Qb, const bf16* __restrict__ Kb,
    float* __restrict__ statC)
{
  const int bh = blockIdx.y;
  const int x = blockIdx.x;              // 0..15
  const int q0a = x * 64, q0b = (31 - x) * 64;
  const int tid = threadIdx.x;
  const int w = tid >> 6, lane = tid & 63, lrow = lane & 15, quad = lane >> 4;
  const bf16* Qh = Qb + (size_t)bh * S * Dh;
  const bf16* Kh = Kb + (size_t)bh * S * Dh;

  int cbase[8];
  #pragma unroll
  for (int cf = 0; cf < 8; ++cf)
    cbase[cf] = (cf < 4) ? (q0a + cf * 16) : (q0b + (cf - 4) * 16);

  bf16x8 kf[8][2];
  #pragma unroll
  for (int cf = 0; cf < 8; ++cf) {
    const bf16* kp = Kh + (size_t)(cbase[cf] + lrow) * Dh + quad * 8;
    kf[cf][0] = *(const bf16x8*)kp;
    kf[cf][1] = *(const bf16x8*)(kp + 32);
  }

  float rm[8], rs[8];
  #pragma unroll
  for (int cf = 0; cf < 8; ++cf) { rm[cf] = NEGBIG; rs[cf] = 0.f; }

  const int qs = q0a + w * 16;
  const bf16* qp0 = Qh + (size_t)(qs + lrow) * Dh + quad * 8;
  bf16x8 a0 = *(const bf16x8*)qp0, a1 = *(const bf16x8*)(qp0 + 32);

  for (int q0 = qs; q0 < S; q0 += 64) {
    bf16x8 n0 = a0, n1 = a1;
    if (q0 + 64 < S) {
      const bf16* np = Qh + (size_t)(q0 + 64 + lrow) * Dh + quad * 8;
      n0 = *(const bf16x8*)np; n1 = *(const bf16x8*)(np + 32);
    }
    #pragma unroll
    for (int cf = 0; cf < 8; ++cf) {
      const int c0f = cbase[cf];
      if (c0f > q0 + 15) continue;          // frag fully masked (uniform)
      floatx4 sacc = {0.f, 0.f, 0.f, 0.f};
      sacc = MFMA16(a0, kf[cf][0], sacc);
      sacc = MFMA16(a1, kf[cf][1], sacc);
      float v0 = sacc[0], v1 = sacc[1], v2 = sacc[2], v3 = sacc[3];
      if (q0 < c0f + 15) {                  // partially masked frag
        int c = c0f + lrow, qb = q0 + quad * 4;
        v0 = (qb + 0 >= c) ? v0 : NEGBIG;
        v1 = (qb + 1 >= c) ? v1 : NEGBIG;
        v2 = (qb + 2 >= c) ? v2 : NEGBIG;
        v3 = (qb + 3 >= c) ? v3 : NEGBIG;
      }
      float mt = fmaxf(fmaxf(v0, v1), fmaxf(v2, v3));
      float nm = fmaxf(rm[cf], mt);
      rs[cf] = rs[cf] * EXP2(rm[cf] - nm)
             + EXP2(v0 - nm) + EXP2(v1 - nm)
             + EXP2(v2 - nm) + EXP2(v3 - nm);
      rm[cf] = nm;
    }
    a0 = n0; a1 = n1;
  }

  #pragma unroll
  for (int cf = 0; cf < 8; ++cf) {
    #pragma unroll
    for (int off = 16; off < 64; off <<= 1) {
      float om = __shfl_xor(rm[cf], off, 64);
      float os = __shfl_xor(rs[cf], off, 64);
      float nm = fmaxf(rm[cf], om);
      rs[cf] = rs[cf] * EXP2(rm[cf] - nm) + os * EXP2(om - nm);
      rm[cf] = nm;
    }
  }

  __shared__ float smm[4][128];
  __shared__ float sms[4][128];
  if (quad == 0) {
    #pragma unroll
    for (int cf = 0; cf < 8; ++cf) {
      smm[w][cf * 16 + lrow] = rm[cf];
      sms[w][cf * 16 + lrow] = rs[cf];
    }
  }
  __syncthreads();
  if (tid < 128) {
    float m = smm[0][tid], sum = sms[0][tid];
    #pragma unroll
    for (int ww = 1; ww < 4; ++ww) {
      float om = smm[ww][tid], os = sms[ww][tid];
      float nm = fmaxf(m, om);
      sum = sum * EXP2(m - nm) + os * EXP2(om - nm);
      m = nm;
    }
    int col = (tid < 64) ? (q0a + tid) : (q0b + tid - 64);
    statC[(size_t)bh * S + col] = m + 3.0f + __log2f(sum);
  }
}

// ---------------------------------------------------------------------------
// Pass 2: out[q,:] = sum_{k<=q} exp2(s[q,k] - C[k]) * V[k,:]
// 256 threads / 4 waves, each wave owns TWO 16-row strips (mi=0,1) — the
// two independent strips give intra-wave ILP that hides MFMA/exp latency;
// 512-thread variants (R2: spilled; R3: lost co-residency, less ILP) were
// 301/111 µs vs this structure's 81.5 µs. Do not split strips across waves.
// x = blockIdx.x directly (R5 xremap regressed — see attn_pass1 note).
// S^T orientation: QK MFMA as (kf, qf) -> lane holds col=q, rows=4
// consecutive key-cols -> P written as ONE ds_write_b64 per frag.
// All LDS XOR-swizzled (128B rows) -> conflict-free.
// ---------------------------------------------------------------------------
__global__ __launch_bounds__(256) void attn_pass2(
    const bf16* __restrict__ Qb, const bf16* __restrict__ Kb,
    const bf16* __restrict__ Vt, const float* __restrict__ statC,
    bf16* __restrict__ AttOut)
{
  const int bh = blockIdx.y;
  const int x = blockIdx.x;              // 0..15
  const int q0a = x * 64, q0b = (31 - x) * 64;
  const int tid = threadIdx.x;
  const int w = tid >> 6, lane = tid & 63, lrow = lane & 15, quad = lane >> 4;
  const bf16* Qh = Qb + (size_t)bh * S * Dh;
  const bf16* Kh = Kb + (size_t)bh * S * Dh;
  const bf16* Vh = Vt + (size_t)bh * Dh * S;   // [d][s]
  const float* sth = statC + (size_t)bh * S;

  __shared__ bf16 sK[64 * 64];         // [s-row][d], swizzled 128B rows
  __shared__ bf16 sV[64 * 64];         // [d-row][s], swizzled
  __shared__ bf16 pbuf[4][32 * 64];    // per-wave P [q-row][c], swizzled

  const int r0m[2] = { q0a + w * 16, q0b + w * 16 };
  bf16x8 qf[2][2];
  #pragma unroll
  for (int mi = 0; mi < 2; ++mi) {
    const bf16* qp = Qh + (size_t)(r0m[mi] + lrow) * Dh + quad * 8;
    qf[mi][0] = *(const bf16x8*)qp;
    qf[mi][1] = *(const bf16x8*)(qp + 32);
  }

  floatx4 zero = {0.f, 0.f, 0.f, 0.f};
  floatx4 accO[2][4];
  #pragma unroll
  for (int mi = 0; mi < 2; ++mi)
    #pragma unroll
    for (int nf = 0; nf < 4; ++nf) accO[mi][nf] = zero;

  const int sr = tid >> 3;        // 0..31
  const int g  = tid & 7;         // 16B granule
  const int nT = 32 - x;          // tiles of 64 cols
  bf16* const pw = &pbuf[w][0];

  // prefetch tile 0 (K, V)
  bf16x8 kg0 = *(const bf16x8*)(Kh + (size_t)sr * Dh + g * 8);
  bf16x8 kg1 = *(const bf16x8*)(Kh + (size_t)(sr + 32) * Dh + g * 8);
  bf16x8 vg0 = *(const bf16x8*)(Vh + (size_t)sr * S + g * 8);
  bf16x8 vg1 = *(const bf16x8*)(Vh + (size_t)(sr + 32) * S + g * 8);

  for (int kt = 0; kt < nT; ++kt) {
    const int kc = kt * 64;
    __syncthreads();
    *(bf16x8*)&sK[swz(sr, g)]      = kg0;
    *(bf16x8*)&sK[swz(sr + 32, g)] = kg1;
    *(bf16x8*)&sV[swz(sr, g)]      = vg0;
    *(bf16x8*)&sV[swz(sr + 32, g)] = vg1;
    // C constants for this tile: quad-uniform float4 per cf (VMEM, L1-served)
    float4 c4[4];
    #pragma unroll
    for (int cf = 0; cf < 4; ++cf)
      c4[cf] = *(const float4*)&sth[kc + cf * 16 + quad * 4];
    __syncthreads();
    if (kt + 1 < nT) {                     // prefetch next K/V tile
      const int kn = kc + 64;
      kg0 = *(const bf16x8*)(Kh + (size_t)(kn + sr) * Dh + g * 8);
      kg1 = *(const bf16x8*)(Kh + (size_t)(kn + sr + 32) * Dh + g * 8);
      vg0 = *(const bf16x8*)(Vh + (size_t)sr * S + kn + g * 8);
      vg1 = *(const bf16x8*)(Vh + (size_t)(sr + 32) * S + kn + g * 8);
    }

    bool actH[2][2];
    #pragma unroll
    for (int mi = 0; mi < 2; ++mi) {
      actH[mi][0] = kc      <= r0m[mi] + 15;
      actH[mi][1] = kc + 32 <= r0m[mi] + 15;
    }

    // ---- S^T = K·Q^T + exp2 phase (cols=q, rows=c) ----
    #pragma unroll
    for (int cf = 0; cf < 4; ++cf) {
      const int hh = cf >> 1;
      if (!actH[0][hh] && !actH[1][hh]) continue;
      const int c0f = kc + cf * 16;
      const int cl = cf * 16;
      bf16x8 kf0 = *(const bf16x8*)&sK[swz(cl + lrow, quad)];
      bf16x8 kf1 = *(const bf16x8*)&sK[swz(cl + lrow, 4 + quad)];
      const float* cc = &c4[cf].x;                 // C[c0f+quad*4+r]
      const int crb = c0f + quad * 4;              // this lane's row base (c)
      #pragma unroll
      for (int mi = 0; mi < 2; ++mi) {
        if (!actH[mi][hh]) continue;
        const int r0 = r0m[mi];
        // dest: row mi*16+lrow, cols cf*16+quad*4..+3 -> one b64
        const int gq = cf * 2 + (quad >> 1);
        const int poff = (mi * 16 + lrow) * 64 +
                         ((gq ^ (lrow & 7)) << 3) + (quad & 1) * 4;
        bf16x4 pk;
        if (c0f > r0 + 15) {               // fully masked frag
          pk[0] = pk[1] = pk[2] = pk[3] = (bf16)0.f;
        } else {
          floatx4 sacc = zero;
          sacc = MFMA16(kf0, qf[mi][0], sacc);     // A=K -> row=c, col=q
          sacc = MFMA16(kf1, qf[mi][1], sacc);
          const bool fullf = (c0f + 15 <= r0);
          const int qlane = r0 + lrow;
          #pragma unroll
          for (int r = 0; r < 4; ++r) {
            float p = EXP2(sacc[r] - cc[r]);
            if (!fullf) p = (crb + r <= qlane) ? p : 0.f;
            pk[r] = (bf16)p;
          }
        }
        *(bf16x4*)(pw + poff) = pk;
      }
    }

    // ---- PV phase (two K=32 halves) ----
    #pragma unroll
    for (int hh = 0; hh < 2; ++hh) {
      if (!actH[0][hh] && !actH[1][hh]) continue;
      bf16x8 vf[4];
      #pragma unroll
      for (int nf = 0; nf < 4; ++nf)
        vf[nf] = *(const bf16x8*)&sV[swz(nf * 16 + lrow, hh * 4 + quad)];
      #pragma unroll
      for (int mi = 0; mi < 2; ++mi) {
        if (!actH[mi][hh]) continue;
        bf16x8 pf = *(const bf16x8*)(pw + swz(mi * 16 + lrow, hh * 4 + quad));
        #pragma unroll
        for (int nf = 0; nf < 4; ++nf)
          accO[mi][nf] = MFMA16(pf, vf[nf], accO[mi][nf]);
      }
    }
  }

  const int b = bh >> 4, h = bh & 15;
  #pragma unroll
  for (int mi = 0; mi < 2; ++mi) {
    #pragma unroll
    for (int nf = 0; nf < 4; ++nf) {
      #pragma unroll
      for (int r = 0; r < 4; ++r) {
        int qq = r0m[mi] + quad * 4 + r;
        int d = nf * 16 + lrow;
        AttOut[((size_t)(b * S + qq)) * DM + h * 64 + d] = (bf16)accO[mi][nf][r];
      }
    }
  }
}

// ---------------------------------------------------------------------------
extern "C" void kernel_launch(void* const* d_in, const int* in_sizes, int n_in,
                              void* d_out, int out_size, void* d_ws, size_t ws_size,
                              hipStream_t stream) {
  (void)in_sizes; (void)n_in; (void)out_size; (void)ws_size;
  const float* queries = (const float*)d_in[0];
  const float* keys    = (const float*)d_in[1];
  const float* values  = (const float*)d_in[2];
  const float* Wq_w = (const float*)d_in[3];  const float* Wq_b = (const float*)d_in[4];
  const float* Wk_w = (const float*)d_in[5];  const float* Wk_b = (const float*)d_in[6];
  const float* Wv_w = (const float*)d_in[7];  const float* Wv_b = (const float*)d_in[8];
  const float* Aq_w = (const float*)d_in[9];  const float* Aq_b = (const float*)d_in[10];
  const float* Bq_w = (const float*)d_in[11]; const float* Bq_b = (const float*)d_in[12];
  const float* Ak_w = (const float*)d_in[13]; const float* Ak_b = (const float*)d_in[14];
  const float* Bk_w = (const float*)d_in[15]; const float* Bk_b = (const float*)d_in[16];
  const float* Av_w = (const float*)d_in[17]; const float* Av_b = (const float*)d_in[18];
  const float* Bv_w = (const float*)d_in[19]; const float* Bv_b = (const float*)d_in[20];
  const float* Wo_w = (const float*)d_in[21]; const float* Wo_b = (const float*)d_in[22];
  float* out = (float*)d_out;

  char* ws = (char*)d_ws;
  size_t off = 0;
  auto alloc = [&](size_t bytes) -> void* {
    void* p = ws + off;
    off += (bytes + 255) & ~(size_t)255;
    return p;
  };
  bf16*  X_all  = (bf16*)alloc((size_t)8192 * 3072 * 2);
  bf16*  Qb     = (bf16*)alloc(QBSZ * 2 * 2);          // Qb || Kb contiguous
  bf16*  Kb     = Qb + QBSZ;
  bf16*  Vt     = (bf16*)alloc((size_t)64 * 64 * 2048 * 2);
  bf16*  AttOut = (bf16*)alloc((size_t)8192 * 1024 * 2);
  bf16*  WqkT   = (bf16*)alloc((size_t)2048 * 1024 * 2);  // WqT || WkT
  bf16*  WvT    = (bf16*)alloc((size_t)1024 * 2048 * 2);
  bf16*  WoT    = (bf16*)alloc((size_t)1024 * 1024 * 2);
  float* bqk    = (float*)alloc(2048 * 4);                // bq || bk
  float* bv     = (float*)alloc(1024 * 4);
  float* bo     = (float*)alloc(1024 * 4);
  float* statC  = (float*)alloc((size_t)64 * 2048 * 4);

  prep_convert<<<8192, 256, 0, stream>>>(queries, keys, values, X_all);
  fold_weights<<<dim3(32, 32), dim3(32, 8), 0, stream>>>(
      Wq_w, Aq_w, Bq_w, Wk_w, Ak_w, Bk_w, Wv_w, Av_w, Bv_w, Wo_w,
      WqkT, WqkT + (size_t)1024 * 1024, WvT, WoT);
  fold_bias<<<4, 256, 0, stream>>>(
      Wq_b, Aq_b, Bq_w, Bq_b, Wk_b, Ak_b, Bk_w, Bk_b,
      Wv_b, Av_b, Bv_w, Bv_b, Wo_b, bqk, bqk + 1024, bv, bo);

  // MERGED Q|K GEMM: M=8192, N=2048, K=1024 -> 1024 blocks = 4/CU
  // (LOG2E pre-folded into WqT/bq by the fold kernels)
  gemm_bf16<<<dim3(16, 64), 512, 0, stream>>>(X_all, 3072, WqkT, 1024, bqk, 8192, 2048, 1024, 1.0f, nullptr, Qb, 1);
  // V computed TRANSPOSED: Vt = WvT @ X^T  (M=1024 rows=(h,d), N=8192=(b,s))
  gemm_bf16<<<dim3(64, 8), 512, 0, stream>>>(WvT, 2048, X_all + 1024, 3072, bv, 1024, 8192, 2048, 1.0f, nullptr, Vt, 3);

  attn_pass1<<<dim3(16, 64), 256, 0, stream>>>(Qb, Kb, statC);
  attn_pass2<<<dim3(16, 64), 256, 0, stream>>>(Qb, Kb, Vt, statC, AttOut);

  gemm_bf16<<<dim3(8, 64), 512, 0, stream>>>(AttOut, 1024, WoT, 1024, bo, 8192, 1024, 1024, 1.0f, out, nullptr, 0);
}

// Round 7
// 433.116 us; speedup vs baseline: 1.0588x; 1.0200x over previous
//
#include <hip/hip_runtime.h>
#include <math.h>
#include <stdint.h>

typedef __bf16 bf16;
typedef __bf16 bf16x8 __attribute__((ext_vector_type(8)));
typedef __bf16 bf16x4 __attribute__((ext_vector_type(4)));
typedef float  floatx4 __attribute__((ext_vector_type(4)));

#define MFMA16(a, b, c) __builtin_amdgcn_mfma_f32_16x16x32_bf16(a, b, c, 0, 0, 0)
#define EXP2(x) __builtin_amdgcn_exp2f(x)

static constexpr int S  = 2048;
static constexpr int DM = 1024;
static constexpr int Dh = 64;
static constexpr size_t QBSZ = (size_t)64 * 2048 * 64;   // elems in Qb (Kb follows)
#define NEGBIG (-1e30f)
#define LOG2E  1.44269504088896340736f

// async global->LDS, 16B per lane; LDS dest = wave-uniform base + lane*16
__device__ __forceinline__ void gload16(const void* g, void* l) {
  __builtin_amdgcn_global_load_lds(
      (const __attribute__((address_space(1))) void*)(uintptr_t)g,
      (__attribute__((address_space(3))) void*)(uintptr_t)l,
      16, 0, 0);
}

// XOR-swizzled LDS offset for 64-elem (128B) rows, granule g (16B) xor'd by
// row&7 (attn tiles).
__device__ __forceinline__ int swz(int row, int g) {
  return row * 64 + ((g ^ (row & 7)) << 3);
}

// ---------------------------------------------------------------------------
// Pack queries|values|keys into one bf16 [8192][3072] buffer (X_all).
// ---------------------------------------------------------------------------
__global__ __launch_bounds__(256) void prep_convert(
    const float* __restrict__ q, const float* __restrict__ k,
    const float* __restrict__ v, bf16* __restrict__ X)
{
  int s = blockIdx.x;
  int c = threadIdx.x * 4;
  size_t src = (size_t)s * DM + c;
  float4 qv = *(const float4*)(q + src);
  float4 vv = *(const float4*)(v + src);
  float4 kv = *(const float4*)(k + src);
  size_t dst = (size_t)s * (3 * DM);
  bf16x4 t;
  t[0] = (bf16)qv.x; t[1] = (bf16)qv.y; t[2] = (bf16)qv.z; t[3] = (bf16)qv.w;
  *(bf16x4*)(X + dst + c) = t;
  t[0] = (bf16)vv.x; t[1] = (bf16)vv.y; t[2] = (bf16)vv.z; t[3] = (bf16)vv.w;
  *(bf16x4*)(X + dst + DM + c) = t;
  t[0] = (bf16)kv.x; t[1] = (bf16)kv.y; t[2] = (bf16)kv.z; t[3] = (bf16)kv.w;
  *(bf16x4*)(X + dst + 2 * DM + c) = t;
}

// ---------------------------------------------------------------------------
// Fold LoRA into effective weights (transposed bf16 for GEMM B-operand).
// Wq gets LOG2E folded in (so the merged Q|K GEMM uses one oscale=1).
// ---------------------------------------------------------------------------
__global__ __launch_bounds__(256) void fold_weights(
    const float* __restrict__ Wq, const float* __restrict__ Aq, const float* __restrict__ Bq,
    const float* __restrict__ Wk, const float* __restrict__ Ak, const float* __restrict__ Bk,
    const float* __restrict__ Wv, const float* __restrict__ Av, const float* __restrict__ Bv,
    const float* __restrict__ Wo,
    bf16* __restrict__ WqT, bf16* __restrict__ WkT,
    bf16* __restrict__ WvT, bf16* __restrict__ WoT)
{
  __shared__ float tile[32][33];
  const int tx = threadIdx.x, ty = threadIdx.y;  // block (32, 8)
  const int n0 = blockIdx.x * 32, k0 = blockIdx.y * 32;
  for (int mi = 0; mi < 5; ++mi) {
    #pragma unroll
    for (int i = 0; i < 4; ++i) {
      int k = k0 + ty + i * 8, n = n0 + tx;
      float val = 0.f;
      if (mi == 0) {
        val = Wq[(size_t)k * DM + n];
        #pragma unroll
        for (int r = 0; r < 8; ++r) val += Aq[k * 8 + r] * Bq[(size_t)r * DM + n];
        val *= LOG2E;
      } else if (mi == 1) {
        val = Wk[(size_t)k * DM + n];
        #pragma unroll
        for (int r = 0; r < 8; ++r) val += Ak[k * 8 + r] * Bk[(size_t)r * DM + n];
      } else if (mi == 2) {
        val = Wv[(size_t)k * DM + n];
      } else if (mi == 3) {
        #pragma unroll
        for (int r = 0; r < 8; ++r) val += Av[k * 8 + r] * Bv[(size_t)r * DM + n];
      } else {
        val = Wo[(size_t)k * DM + n];
      }
      tile[ty + i * 8][tx] = val;
    }
    __syncthreads();
    #pragma unroll
    for (int i = 0; i < 4; ++i) {
      int n = n0 + ty + i * 8, k = k0 + tx;
      float val = tile[tx][ty + i * 8];
      if (mi == 0)      WqT[(size_t)n * DM + k] = (bf16)val;
      else if (mi == 1) WkT[(size_t)n * DM + k] = (bf16)val;
      else if (mi == 2) WvT[(size_t)n * 2048 + k] = (bf16)val;
      else if (mi == 3) WvT[(size_t)n * 2048 + 1024 + k] = (bf16)val;
      else              WoT[(size_t)n * DM + k] = (bf16)val;
    }
    __syncthreads();
  }
}

__global__ __launch_bounds__(256) void fold_bias(
    const float* __restrict__ Wqb, const float* __restrict__ Aqb,
    const float* __restrict__ BqW, const float* __restrict__ Bqb,
    const float* __restrict__ Wkb, const float* __restrict__ Akb,
    const float* __restrict__ BkW, const float* __restrict__ Bkb,
    const float* __restrict__ Wvb, const float* __restrict__ Avb,
    const float* __restrict__ BvW, const float* __restrict__ Bvb,
    const float* __restrict__ Wob,
    float* __restrict__ bq, float* __restrict__ bk,
    float* __restrict__ bv, float* __restrict__ bo)
{
  int n = blockIdx.x * 256 + threadIdx.x;
  float aq = Wqb[n] + Bqb[n];
  float ak = Wkb[n] + Bkb[n];
  float av = Wvb[n] + Bvb[n];
  #pragma unroll
  for (int r = 0; r < 8; ++r) {
    aq += Aqb[r] * BqW[(size_t)r * DM + n];
    ak += Akb[r] * BkW[(size_t)r * DM + n];
    av += Avb[r] * BvW[(size_t)r * DM + n];
  }
  bq[n] = aq * LOG2E;            // LOG2E folded (merged Q|K GEMM, oscale=1)
  bk[n] = ak; bv[n] = av; bo[n] = Wob[n];
}

// ---------------------------------------------------------------------------
// 128x128 bf16 MFMA GEMM, 512 threads / 8 waves (32x64 per wave).
// T4 counted-vmcnt pipeline: 3-slot LDS ring, prefetch depth 2, raw
// s_barrier + asm vmcnt(2) -> global_load_lds stays in flight ACROSS
// barriers (never drained mid-loop). Safety: slot (t+2)%3 == (t-1)%3 is
// re-issued only after the barrier proving all waves finished reading it.
// Source-pre-swizzled staging (granule ^= (row>>1)&3): frag reads ~conflict-free.
// mode 0: fp32 [M][N] (+col bias)
// mode 1: MERGED Q|K: N=2048, cols [0,1024) -> Qb, [1024,2048) -> Kb.
// mode 3: bf16 [bh][d][s] scatter (+ROW bias)     (V computed transposed)
// ---------------------------------------------------------------------------
__global__ __launch_bounds__(512, 4) void gemm_bf16(
    const bf16* __restrict__ A, int lda,
    const bf16* __restrict__ BT, int ldb,
    const float* __restrict__ bias,
    int M, int N, int K, float oscale,
    float* __restrict__ outF, bf16* __restrict__ outB, int mode)
{
  __shared__ bf16 sA[3][128 * 32];
  __shared__ bf16 sB[3][128 * 32];
  const int tid = threadIdx.x;
  const int bm0 = blockIdx.y * 128, bn0 = blockIdx.x * 128;
  const int w = tid >> 6, lane = tid & 63, lrow = lane & 15, quad = lane >> 4;
  const int wm = (w >> 1) * 32, wn = (w & 1) * 64;

  // merged Q|K: n-blocks in the upper half read the keys columns of X_all
  const bf16* Abase = (mode == 1) ? (A + (size_t)(bn0 >> 10) * 2048) : A;

  // staging: thread t loads ONE 16B granule of A and B per K-step.
  const int srow = tid >> 2;                        // 0..127
  const int sg   = (tid & 3) ^ ((srow >> 1) & 3);   // pre-swizzled src granule
  const bf16* Ag = Abase + (size_t)(bm0 + srow) * lda + sg * 8;
  const bf16* Bg = BT + (size_t)(bn0 + srow) * ldb + sg * 8;
  const int wb = w * 512;      // per-wave LDS base (elements; 1024 B/wave)

  // swizzled fragment element offsets (row r granule quad -> slot quad^((r>>1)&3))
  int aoff[2], boff[4];
  #pragma unroll
  for (int i = 0; i < 2; ++i) {
    int r = wm + i * 16 + lrow;
    aoff[i] = r * 32 + ((quad ^ ((r >> 1) & 3)) << 3);
  }
  #pragma unroll
  for (int j = 0; j < 4; ++j) {
    int r = wn + j * 16 + lrow;
    boff[j] = r * 32 + ((quad ^ ((r >> 1) & 3)) << 3);
  }

  floatx4 zero = {0.f, 0.f, 0.f, 0.f};
  floatx4 acc[2][4];
  #pragma unroll
  for (int i = 0; i < 2; ++i)
    #pragma unroll
    for (int j = 0; j < 4; ++j) acc[i][j] = zero;

  const int nk = K >> 5;                 // >= 32 for all call sites
  // prologue: stage K-steps 0 and 1 (4 loads outstanding)
  gload16(Ag,      &sA[0][wb]);
  gload16(Bg,      &sB[0][wb]);
  gload16(Ag + 32, &sA[1][wb]);
  gload16(Bg + 32, &sB[1][wb]);

  int cur = 0;
  for (int t = 0; t < nk; ++t) {
    if (t + 1 < nk) {
      asm volatile("s_waitcnt vmcnt(2)" ::: "memory");   // step t landed
    } else {
      asm volatile("s_waitcnt vmcnt(0)" ::: "memory");   // final step
    }
    __builtin_amdgcn_s_barrier();        // all waves' step-t staging visible,
                                         // all waves done reading slot (t-1)%3
    if (t + 2 < nk) {                    // refill slot (t+2)%3 == (t-1)%3
      int nxt = cur + 2; if (nxt >= 3) nxt -= 3;
      gload16(Ag + (size_t)(t + 2) * 32, &sA[nxt][wb]);
      gload16(Bg + (size_t)(t + 2) * 32, &sB[nxt][wb]);
    }
    bf16x8 aF[2], bF[4];
    #pragma unroll
    for (int i = 0; i < 2; ++i) aF[i] = *(const bf16x8*)&sA[cur][aoff[i]];
    #pragma unroll
    for (int j = 0; j < 4; ++j) bF[j] = *(const bf16x8*)&sB[cur][boff[j]];
    #pragma unroll
    for (int i = 0; i < 2; ++i)
      #pragma unroll
      for (int j = 0; j < 4; ++j)
        acc[i][j] = MFMA16(aF[i], bF[j], acc[i][j]);
    cur = (cur == 2) ? 0 : cur + 1;
  }

  if (mode == 3) {                       // row bias, [bh][d][s] coalesced
    #pragma unroll
    for (int i = 0; i < 2; ++i) {
      #pragma unroll
      for (int r = 0; r < 4; ++r) {
        int gm = bm0 + wm + i * 16 + quad * 4 + r;   // (h,d)
        float bvr = bias[gm];
        int h = gm >> 6, d = gm & 63;
        #pragma unroll
        for (int j = 0; j < 4; ++j) {
          int gn = bn0 + wn + j * 16 + lrow;          // (b,s)
          int b = gn >> 11, s = gn & 2047;
          outB[((size_t)(b * 16 + h) * 64 + d) * 2048 + s] =
              (bf16)(acc[i][j][r] + bvr);
        }
      }
    }
    return;
  }

  float bvs[4];
  #pragma unroll
  for (int j = 0; j < 4; ++j) bvs[j] = bias[bn0 + wn + j * 16 + lrow];

  #pragma unroll
  for (int i = 0; i < 2; ++i) {
    #pragma unroll
    for (int j = 0; j < 4; ++j) {
      #pragma unroll
      for (int r = 0; r < 4; ++r) {
        int gm = bm0 + wm + i * 16 + quad * 4 + r;
        int gn = bn0 + wn + j * 16 + lrow;
        float v = (acc[i][j][r] + bvs[j]) * oscale;
        if (mode == 0) {
          outF[(size_t)gm * N + gn] = v;
        } else {
          // merged Q|K scatter: part 0 -> Qb, part 1 -> Kb (contiguous)
          int b = gm >> 11, s = gm & 2047;
          int part = gn >> 10, h = (gn >> 6) & 15, d = gn & 63;
          outB[(size_t)part * QBSZ +
               ((size_t)(b * 16 + h) * 2048 + s) * 64 + d] = (bf16)v;
        }
      }
    }
  }
}

// ---------------------------------------------------------------------------
// Pass 1 (log2 domain; Q pre-scaled by log2e): per-column exp2-sum over q>=c.
// NO running max: scores are bounded (|s| << 127 in log2 domain), so
// fp32 exp2 sums cannot overflow; C[c] = 3 + log2(sum) is mathematically
// identical to the max-tracked form. Removes ~10 VALU + 1 trans per cf-step.
// x = blockIdx.x directly (R5 xremap regressed: dispatch time is set by the
// long x=0 blocks, which need co-resident company for latency hiding).
// ---------------------------------------------------------------------------
__global__ __launch_bounds__(256) void attn_pass1(
    const bf16* __restrict__ Qb, const bf16* __restrict__ Kb,
    float* __restrict__ statC)
{
  const int bh = blockIdx.y;
  const int x = blockIdx.x;              // 0..15
  const int q0a = x * 64, q0b = (31 - x) * 64;
  const int tid = threadIdx.x;
  const int w = tid >> 6, lane = tid & 63, lrow = lane & 15, quad = lane >> 4;
  const bf16* Qh = Qb + (size_t)bh * S * Dh;
  const bf16* Kh = Kb + (size_t)bh * S * Dh;

  int cbase[8];
  #pragma unroll
  for (int cf = 0; cf < 8; ++cf)
    cbase[cf] = (cf < 4) ? (q0a + cf * 16) : (q0b + (cf - 4) * 16);

  bf16x8 kf[8][2];
  #pragma unroll
  for (int cf = 0; cf < 8; ++cf) {
    const bf16* kp = Kh + (size_t)(cbase[cf] + lrow) * Dh + quad * 8;
    kf[cf][0] = *(const bf16x8*)kp;
    kf[cf][1] = *(const bf16x8*)(kp + 32);
  }

  float rs[8];
  #pragma unroll
  for (int cf = 0; cf < 8; ++cf) rs[cf] = 0.f;

  const int qs = q0a + w * 16;
  const bf16* qp0 = Qh + (size_t)(qs + lrow) * Dh + quad * 8;
  bf16x8 a0 = *(const bf16x8*)qp0, a1 = *(const bf16x8*)(qp0 + 32);

  for (int q0 = qs; q0 < S; q0 += 64) {
    bf16x8 n0 = a0, n1 = a1;
    if (q0 + 64 < S) {
      const bf16* np = Qh + (size_t)(q0 + 64 + lrow) * Dh + quad * 8;
      n0 = *(const bf16x8*)np; n1 = *(const bf16x8*)(np + 32);
    }
    #pragma unroll
    for (int cf = 0; cf < 8; ++cf) {
      const int c0f = cbase[cf];
      if (c0f > q0 + 15) continue;          // frag fully masked (uniform)
      floatx4 sacc = {0.f, 0.f, 0.f, 0.f};
      sacc = MFMA16(a0, kf[cf][0], sacc);
      sacc = MFMA16(a1, kf[cf][1], sacc);
      float e0 = EXP2(sacc[0]), e1 = EXP2(sacc[1]);
      float e2 = EXP2(sacc[2]), e3 = EXP2(sacc[3]);
      if (q0 < c0f + 15) {                  // partially masked frag
        int c = c0f + lrow, qb = q0 + quad * 4;
        e0 = (qb + 0 >= c) ? e0 : 0.f;
        e1 = (qb + 1 >= c) ? e1 : 0.f;
        e2 = (qb + 2 >= c) ? e2 : 0.f;
        e3 = (qb + 3 >= c) ? e3 : 0.f;
      }
      rs[cf] += (e0 + e1) + (e2 + e3);
    }
    a0 = n0; a1 = n1;
  }

  #pragma unroll
  for (int cf = 0; cf < 8; ++cf) {
    rs[cf] += __shfl_xor(rs[cf], 16, 64);
    rs[cf] += __shfl_xor(rs[cf], 32, 64);
  }

  __shared__ float sms[4][128];
  if (quad == 0) {
    #pragma unroll
    for (int cf = 0; cf < 8; ++cf)
      sms[w][cf * 16 + lrow] = rs[cf];
  }
  __syncthreads();
  if (tid < 128) {
    float sum = (sms[0][tid] + sms[1][tid]) + (sms[2][tid] + sms[3][tid]);
    int col = (tid < 64) ? (q0a + tid) : (q0b + tid - 64);
    statC[(size_t)bh * S + col] = 3.0f + __log2f(sum);
  }
}

// ---------------------------------------------------------------------------
// Pass 2: out[q,:] = sum_{k<=q} exp2(s[q,k] - C[k]) * V[k,:]
// 256 threads / 4 waves, each wave owns TWO 16-row strips (mi=0,1) — the
// two independent strips give intra-wave ILP that hides MFMA/exp latency;
// 512-thread variants (R2: spilled; R3: lost co-residency, less ILP) were
// 301/111 µs vs this structure's 81.5 µs. Do not split strips across waves.
// x = blockIdx.x directly (R5 xremap regressed — see attn_pass1 note).
// S^T orientation: QK MFMA as (kf, qf) -> lane holds col=q, rows=4
// consecutive key-cols -> P written as ONE ds_write_b64 per frag.
// All LDS XOR-swizzled (128B rows) -> conflict-free.
// ---------------------------------------------------------------------------
__global__ __launch_bounds__(256) void attn_pass2(
    const bf16* __restrict__ Qb, const bf16* __restrict__ Kb,
    const bf16* __restrict__ Vt, const float* __restrict__ statC,
    bf16* __restrict__ AttOut)
{
  const int bh = blockIdx.y;
  const int x = blockIdx.x;              // 0..15
  const int q0a = x * 64, q0b = (31 - x) * 64;
  const int tid = threadIdx.x;
  const int w = tid >> 6, lane = tid & 63, lrow = lane & 15, quad = lane >> 4;
  const bf16* Qh = Qb + (size_t)bh * S * Dh;
  const bf16* Kh = Kb + (size_t)bh * S * Dh;
  const bf16* Vh = Vt + (size_t)bh * Dh * S;   // [d][s]
  const float* sth = statC + (size_t)bh * S;

  __shared__ bf16 sK[64 * 64];         // [s-row][d], swizzled 128B rows
  __shared__ bf16 sV[64 * 64];         // [d-row][s], swizzled
  __shared__ bf16 pbuf[4][32 * 64];    // per-wave P [q-row][c], swizzled

  const int r0m[2] = { q0a + w * 16, q0b + w * 16 };
  bf16x8 qf[2][2];
  #pragma unroll
  for (int mi = 0; mi < 2; ++mi) {
    const bf16* qp = Qh + (size_t)(r0m[mi] + lrow) * Dh + quad * 8;
    qf[mi][0] = *(const bf16x8*)qp;
    qf[mi][1] = *(const bf16x8*)(qp + 32);
  }

  floatx4 zero = {0.f, 0.f, 0.f, 0.f};
  floatx4 accO[2][4];
  #pragma unroll
  for (int mi = 0; mi < 2; ++mi)
    #pragma unroll
    for (int nf = 0; nf < 4; ++nf) accO[mi][nf] = zero;

  const int sr = tid >> 3;        // 0..31
  const int g  = tid & 7;         // 16B granule
  const int nT = 32 - x;          // tiles of 64 cols
  bf16* const pw = &pbuf[w][0];

  // prefetch tile 0 (K, V)
  bf16x8 kg0 = *(const bf16x8*)(Kh + (size_t)sr * Dh + g * 8);
  bf16x8 kg1 = *(const bf16x8*)(Kh + (size_t)(sr + 32) * Dh + g * 8);
  bf16x8 vg0 = *(const bf16x8*)(Vh + (size_t)sr * S + g * 8);
  bf16x8 vg1 = *(const bf16x8*)(Vh + (size_t)(sr + 32) * S + g * 8);

  for (int kt = 0; kt < nT; ++kt) {
    const int kc = kt * 64;
    __syncthreads();
    *(bf16x8*)&sK[swz(sr, g)]      = kg0;
    *(bf16x8*)&sK[swz(sr + 32, g)] = kg1;
    *(bf16x8*)&sV[swz(sr, g)]      = vg0;
    *(bf16x8*)&sV[swz(sr + 32, g)] = vg1;
    // C constants for this tile: quad-uniform float4 per cf (VMEM, L1-served)
    float4 c4[4];
    #pragma unroll
    for (int cf = 0; cf < 4; ++cf)
      c4[cf] = *(const float4*)&sth[kc + cf * 16 + quad * 4];
    __syncthreads();
    if (kt + 1 < nT) {                     // prefetch next K/V tile
      const int kn = kc + 64;
      kg0 = *(const bf16x8*)(Kh + (size_t)(kn + sr) * Dh + g * 8);
      kg1 = *(const bf16x8*)(Kh + (size_t)(kn + sr + 32) * Dh + g * 8);
      vg0 = *(const bf16x8*)(Vh + (size_t)sr * S + kn + g * 8);
      vg1 = *(const bf16x8*)(Vh + (size_t)(sr + 32) * S + kn + g * 8);
    }

    bool actH[2][2];
    #pragma unroll
    for (int mi = 0; mi < 2; ++mi) {
      actH[mi][0] = kc      <= r0m[mi] + 15;
      actH[mi][1] = kc + 32 <= r0m[mi] + 15;
    }

    // ---- S^T = K·Q^T + exp2 phase (cols=q, rows=c) ----
    #pragma unroll
    for (int cf = 0; cf < 4; ++cf) {
      const int hh = cf >> 1;
      if (!actH[0][hh] && !actH[1][hh]) continue;
      const int c0f = kc + cf * 16;
      const int cl = cf * 16;
      bf16x8 kf0 = *(const bf16x8*)&sK[swz(cl + lrow, quad)];
      bf16x8 kf1 = *(const bf16x8*)&sK[swz(cl + lrow, 4 + quad)];
      const float* cc = &c4[cf].x;                 // C[c0f+quad*4+r]
      const int crb = c0f + quad * 4;              // this lane's row base (c)
      #pragma unroll
      for (int mi = 0; mi < 2; ++mi) {
        if (!actH[mi][hh]) continue;
        const int r0 = r0m[mi];
        // dest: row mi*16+lrow, cols cf*16+quad*4..+3 -> one b64
        const int gq = cf * 2 + (quad >> 1);
        const int poff = (mi * 16 + lrow) * 64 +
                         ((gq ^ (lrow & 7)) << 3) + (quad & 1) * 4;
        bf16x4 pk;
        if (c0f > r0 + 15) {               // fully masked frag
          pk[0] = pk[1] = pk[2] = pk[3] = (bf16)0.f;
        } else {
          floatx4 sacc = zero;
          sacc = MFMA16(kf0, qf[mi][0], sacc);     // A=K -> row=c, col=q
          sacc = MFMA16(kf1, qf[mi][1], sacc);
          const bool fullf = (c0f + 15 <= r0);
          const int qlane = r0 + lrow;
          #pragma unroll
          for (int r = 0; r < 4; ++r) {
            float p = EXP2(sacc[r] - cc[r]);
            if (!fullf) p = (crb + r <= qlane) ? p : 0.f;
            pk[r] = (bf16)p;
          }
        }
        *(bf16x4*)(pw + poff) = pk;
      }
    }

    // ---- PV phase (two K=32 halves) ----
    #pragma unroll
    for (int hh = 0; hh < 2; ++hh) {
      if (!actH[0][hh] && !actH[1][hh]) continue;
      bf16x8 vf[4];
      #pragma unroll
      for (int nf = 0; nf < 4; ++nf)
        vf[nf] = *(const bf16x8*)&sV[swz(nf * 16 + lrow, hh * 4 + quad)];
      #pragma unroll
      for (int mi = 0; mi < 2; ++mi) {
        if (!actH[mi][hh]) continue;
        bf16x8 pf = *(const bf16x8*)(pw + swz(mi * 16 + lrow, hh * 4 + quad));
        #pragma unroll
        for (int nf = 0; nf < 4; ++nf)
          accO[mi][nf] = MFMA16(pf, vf[nf], accO[mi][nf]);
      }
    }
  }

  const int b = bh >> 4, h = bh & 15;
  #pragma unroll
  for (int mi = 0; mi < 2; ++mi) {
    #pragma unroll
    for (int nf = 0; nf < 4; ++nf) {
      #pragma unroll
      for (int r = 0; r < 4; ++r) {
        int qq = r0m[mi] + quad * 4 + r;
        int d = nf * 16 + lrow;
        AttOut[((size_t)(b * S + qq)) * DM + h * 64 + d] = (bf16)accO[mi][nf][r];
      }
    }
  }
}

// ---------------------------------------------------------------------------
extern "C" void kernel_launch(void* const* d_in, const int* in_sizes, int n_in,
                              void* d_out, int out_size, void* d_ws, size_t ws_size,
                              hipStream_t stream) {
  (void)in_sizes; (void)n_in; (void)out_size; (void)ws_size;
  const float* queries = (const float*)d_in[0];
  const float* keys    = (const float*)d_in[1];
  const float* values  = (const float*)d_in[2];
  const float* Wq_w = (const float*)d_in[3];  const float* Wq_b = (const float*)d_in[4];
  const float* Wk_w = (const float*)d_in[5];  const float* Wk_b = (const float*)d_in[6];
  const float* Wv_w = (const float*)d_in[7];  const float* Wv_b = (const float*)d_in[8];
  const float* Aq_w = (const float*)d_in[9];  const float* Aq_b = (const float*)d_in[10];
  const float* Bq_w = (const float*)d_in[11]; const float* Bq_b = (const float*)d_in[12];
  const float* Ak_w = (const float*)d_in[13]; const float* Ak_b = (const float*)d_in[14];
  const float* Bk_w = (const float*)d_in[15]; const float* Bk_b = (const float*)d_in[16];
  const float* Av_w = (const float*)d_in[17]; const float* Av_b = (const float*)d_in[18];
  const float* Bv_w = (const float*)d_in[19]; const float* Bv_b = (const float*)d_in[20];
  const float* Wo_w = (const float*)d_in[21]; const float* Wo_b = (const float*)d_in[22];
  float* out = (float*)d_out;

  char* ws = (char*)d_ws;
  size_t off = 0;
  auto alloc = [&](size_t bytes) -> void* {
    void* p = ws + off;
    off += (bytes + 255) & ~(size_t)255;
    return p;
  };
  bf16*  X_all  = (bf16*)alloc((size_t)8192 * 3072 * 2);
  bf16*  Qb     = (bf16*)alloc(QBSZ * 2 * 2);          // Qb || Kb contiguous
  bf16*  Kb     = Qb + QBSZ;
  bf16*  Vt     = (bf16*)alloc((size_t)64 * 64 * 2048 * 2);
  bf16*  AttOut = (bf16*)alloc((size_t)8192 * 1024 * 2);
  bf16*  WqkT   = (bf16*)alloc((size_t)2048 * 1024 * 2);  // WqT || WkT
  bf16*  WvT    = (bf16*)alloc((size_t)1024 * 2048 * 2);
  bf16*  WoT    = (bf16*)alloc((size_t)1024 * 1024 * 2);
  float* bqk    = (float*)alloc(2048 * 4);                // bq || bk
  float* bv     = (float*)alloc(1024 * 4);
  float* bo     = (float*)alloc(1024 * 4);
  float* statC  = (float*)alloc((size_t)64 * 2048 * 4);

  prep_convert<<<8192, 256, 0, stream>>>(queries, keys, values, X_all);
  fold_weights<<<dim3(32, 32), dim3(32, 8), 0, stream>>>(
      Wq_w, Aq_w, Bq_w, Wk_w, Ak_w, Bk_w, Wv_w, Av_w, Bv_w, Wo_w,
      WqkT, WqkT + (size_t)1024 * 1024, WvT, WoT);
  fold_bias<<<4, 256, 0, stream>>>(
      Wq_b, Aq_b, Bq_w, Bq_b, Wk_b, Ak_b, Bk_w, Bk_b,
      Wv_b, Av_b, Bv_w, Bv_b, Wo_b, bqk, bqk + 1024, bv, bo);

  // MERGED Q|K GEMM: M=8192, N=2048, K=1024 -> 1024 blocks
  gemm_bf16<<<dim3(16, 64), 512, 0, stream>>>(X_all, 3072, WqkT, 1024, bqk, 8192, 2048, 1024, 1.0f, nullptr, Qb, 1);
  // V computed TRANSPOSED: Vt = WvT @ X^T  (M=1024 rows=(h,d), N=8192=(b,s))
  gemm_bf16<<<dim3(64, 8), 512, 0, stream>>>(WvT, 2048, X_all + 1024, 3072, bv, 1024, 8192, 2048, 1.0f, nullptr, Vt, 3);

  attn_pass1<<<dim3(16, 64), 256, 0, stream>>>(Qb, Kb, statC);
  attn_pass2<<<dim3(16, 64), 256, 0, stream>>>(Qb, Kb, Vt, statC, AttOut);

  gemm_bf16<<<dim3(8, 64), 512, 0, stream>>>(AttOut, 1024, WoT, 1024, bo, 8192, 1024, 1024, 1.0f, out, nullptr, 0);
}

// Round 8
// 425.039 us; speedup vs baseline: 1.0790x; 1.0190x over previous
//
#include <hip/hip_runtime.h>
#include <math.h>
#include <stdint.h>

typedef __bf16 bf16;
typedef __bf16 bf16x8 __attribute__((ext_vector_type(8)));
typedef __bf16 bf16x4 __attribute__((ext_vector_type(4)));
typedef float  floatx4 __attribute__((ext_vector_type(4)));

#define MFMA16(a, b, c) __builtin_amdgcn_mfma_f32_16x16x32_bf16(a, b, c, 0, 0, 0)
#define EXP2(x) __builtin_amdgcn_exp2f(x)

static constexpr int S  = 2048;
static constexpr int DM = 1024;
static constexpr int Dh = 64;
static constexpr size_t QBSZ = (size_t)64 * 2048 * 64;   // elems in Qb (Kb follows)
#define NEGBIG (-1e30f)
#define LOG2E  1.44269504088896340736f

// async global->LDS, 16B per lane; LDS dest = wave-uniform base + lane*16
__device__ __forceinline__ void gload16(const void* g, void* l) {
  __builtin_amdgcn_global_load_lds(
      (const __attribute__((address_space(1))) void*)(uintptr_t)g,
      (__attribute__((address_space(3))) void*)(uintptr_t)l,
      16, 0, 0);
}

// XOR-swizzled LDS offset for 64-elem (128B) rows, granule g (16B) xor'd by
// row&7 (attn tiles).
__device__ __forceinline__ int swz(int row, int g) {
  return row * 64 + ((g ^ (row & 7)) << 3);
}

// ---------------------------------------------------------------------------
// Pack queries|values|keys into one bf16 [8192][3072] buffer (X_all).
// ---------------------------------------------------------------------------
__global__ __launch_bounds__(256) void prep_convert(
    const float* __restrict__ q, const float* __restrict__ k,
    const float* __restrict__ v, bf16* __restrict__ X)
{
  int s = blockIdx.x;
  int c = threadIdx.x * 4;
  size_t src = (size_t)s * DM + c;
  float4 qv = *(const float4*)(q + src);
  float4 vv = *(const float4*)(v + src);
  float4 kv = *(const float4*)(k + src);
  size_t dst = (size_t)s * (3 * DM);
  bf16x4 t;
  t[0] = (bf16)qv.x; t[1] = (bf16)qv.y; t[2] = (bf16)qv.z; t[3] = (bf16)qv.w;
  *(bf16x4*)(X + dst + c) = t;
  t[0] = (bf16)vv.x; t[1] = (bf16)vv.y; t[2] = (bf16)vv.z; t[3] = (bf16)vv.w;
  *(bf16x4*)(X + dst + DM + c) = t;
  t[0] = (bf16)kv.x; t[1] = (bf16)kv.y; t[2] = (bf16)kv.z; t[3] = (bf16)kv.w;
  *(bf16x4*)(X + dst + 2 * DM + c) = t;
}

// ---------------------------------------------------------------------------
// Fold LoRA into effective weights (transposed bf16 for GEMM B-operand).
// Wq gets LOG2E folded in (so the merged Q|K GEMM uses one oscale=1).
// ---------------------------------------------------------------------------
__global__ __launch_bounds__(256) void fold_weights(
    const float* __restrict__ Wq, const float* __restrict__ Aq, const float* __restrict__ Bq,
    const float* __restrict__ Wk, const float* __restrict__ Ak, const float* __restrict__ Bk,
    const float* __restrict__ Wv, const float* __restrict__ Av, const float* __restrict__ Bv,
    const float* __restrict__ Wo,
    bf16* __restrict__ WqT, bf16* __restrict__ WkT,
    bf16* __restrict__ WvT, bf16* __restrict__ WoT)
{
  __shared__ float tile[32][33];
  const int tx = threadIdx.x, ty = threadIdx.y;  // block (32, 8)
  const int n0 = blockIdx.x * 32, k0 = blockIdx.y * 32;
  for (int mi = 0; mi < 5; ++mi) {
    #pragma unroll
    for (int i = 0; i < 4; ++i) {
      int k = k0 + ty + i * 8, n = n0 + tx;
      float val = 0.f;
      if (mi == 0) {
        val = Wq[(size_t)k * DM + n];
        #pragma unroll
        for (int r = 0; r < 8; ++r) val += Aq[k * 8 + r] * Bq[(size_t)r * DM + n];
        val *= LOG2E;
      } else if (mi == 1) {
        val = Wk[(size_t)k * DM + n];
        #pragma unroll
        for (int r = 0; r < 8; ++r) val += Ak[k * 8 + r] * Bk[(size_t)r * DM + n];
      } else if (mi == 2) {
        val = Wv[(size_t)k * DM + n];
      } else if (mi == 3) {
        #pragma unroll
        for (int r = 0; r < 8; ++r) val += Av[k * 8 + r] * Bv[(size_t)r * DM + n];
      } else {
        val = Wo[(size_t)k * DM + n];
      }
      tile[ty + i * 8][tx] = val;
    }
    __syncthreads();
    #pragma unroll
    for (int i = 0; i < 4; ++i) {
      int n = n0 + ty + i * 8, k = k0 + tx;
      float val = tile[tx][ty + i * 8];
      if (mi == 0)      WqT[(size_t)n * DM + k] = (bf16)val;
      else if (mi == 1) WkT[(size_t)n * DM + k] = (bf16)val;
      else if (mi == 2) WvT[(size_t)n * 2048 + k] = (bf16)val;
      else if (mi == 3) WvT[(size_t)n * 2048 + 1024 + k] = (bf16)val;
      else              WoT[(size_t)n * DM + k] = (bf16)val;
    }
    __syncthreads();
  }
}

__global__ __launch_bounds__(256) void fold_bias(
    const float* __restrict__ Wqb, const float* __restrict__ Aqb,
    const float* __restrict__ BqW, const float* __restrict__ Bqb,
    const float* __restrict__ Wkb, const float* __restrict__ Akb,
    const float* __restrict__ BkW, const float* __restrict__ Bkb,
    const float* __restrict__ Wvb, const float* __restrict__ Avb,
    const float* __restrict__ BvW, const float* __restrict__ Bvb,
    const float* __restrict__ Wob,
    float* __restrict__ bq, float* __restrict__ bk,
    float* __restrict__ bv, float* __restrict__ bo)
{
  int n = blockIdx.x * 256 + threadIdx.x;
  float aq = Wqb[n] + Bqb[n];
  float ak = Wkb[n] + Bkb[n];
  float av = Wvb[n] + Bvb[n];
  #pragma unroll
  for (int r = 0; r < 8; ++r) {
    aq += Aqb[r] * BqW[(size_t)r * DM + n];
    ak += Akb[r] * BkW[(size_t)r * DM + n];
    av += Avb[r] * BvW[(size_t)r * DM + n];
  }
  bq[n] = aq * LOG2E;            // LOG2E folded (merged Q|K GEMM, oscale=1)
  bk[n] = ak; bv[n] = av; bo[n] = Wob[n];
}

// ---------------------------------------------------------------------------
// m97-shape 128x128 bf16 MFMA GEMM: 256 threads / 4 waves, each wave owns a
// 64x64 sub-tile (acc 4x4) -> 16 MFMA per K-step per wave (2x the 8-wave
// variant: fixed per-step costs amortized over twice the MFMA).
// T4 counted-vmcnt pipeline: 3-slot LDS ring (48 KB), prefetch depth 2,
// raw s_barrier + asm vmcnt(4) -> staging loads stay in flight across
// barriers. Slot (t+2)%3 == (t-1)%3 re-issued only after the barrier
// proving all waves finished reading it.
// Staging: each thread loads granules tid and tid+256 of A and B
// (pre-swizzled source granule (tid&3)^((row>>1)&3); linear LDS dest).
// mode 0: fp32 [M][N] (+col bias)
// mode 1: MERGED Q|K: N=2048, cols [0,1024) -> Qb, [1024,2048) -> Kb.
// mode 3: bf16 [bh][d][s] scatter (+ROW bias)     (V computed transposed)
// ---------------------------------------------------------------------------
__global__ __launch_bounds__(256) void gemm_bf16(
    const bf16* __restrict__ A, int lda,
    const bf16* __restrict__ BT, int ldb,
    const float* __restrict__ bias,
    int M, int N, int K, float oscale,
    float* __restrict__ outF, bf16* __restrict__ outB, int mode)
{
  __shared__ bf16 sA[3][128 * 32];
  __shared__ bf16 sB[3][128 * 32];
  const int tid = threadIdx.x;
  const int bm0 = blockIdx.y * 128, bn0 = blockIdx.x * 128;
  const int w = tid >> 6, lane = tid & 63, lrow = lane & 15, quad = lane >> 4;
  const int wm = (w >> 1) * 64, wn = (w & 1) * 64;

  // merged Q|K: n-blocks in the upper half read the keys columns of X_all
  const bf16* Abase = (mode == 1) ? (A + (size_t)(bn0 >> 10) * 2048) : A;

  // staging: thread t loads granules t and t+256 (rows r0 and r0+64).
  const int r0 = tid >> 2;                       // 0..63
  const int c0 = (tid & 3) ^ ((r0 >> 1) & 3);    // pre-swizzled src granule
  // ((r0+64)>>1)&3 == (r0>>1)&3 (64/2 = 32 ≡ 0 mod 4) -> same c0 for row+64
  const bf16* Ag0 = Abase + (size_t)(bm0 + r0) * lda + c0 * 8;
  const bf16* Ag1 = Abase + (size_t)(bm0 + r0 + 64) * lda + c0 * 8;
  const bf16* Bg0 = BT + (size_t)(bn0 + r0) * ldb + c0 * 8;
  const bf16* Bg1 = BT + (size_t)(bn0 + r0 + 64) * ldb + c0 * 8;
  const int wb0 = w * 512;            // LDS elem base (wave-uniform), lane*16B added by HW
  const int wb1 = 2048 + w * 512;

  // swizzled fragment element offsets (row r granule quad -> slot quad^((r>>1)&3))
  int aoff[4], boff[4];
  #pragma unroll
  for (int i = 0; i < 4; ++i) {
    int ra = wm + i * 16 + lrow;
    aoff[i] = ra * 32 + ((quad ^ ((ra >> 1) & 3)) << 3);
    int rb = wn + i * 16 + lrow;
    boff[i] = rb * 32 + ((quad ^ ((rb >> 1) & 3)) << 3);
  }

  floatx4 zero = {0.f, 0.f, 0.f, 0.f};
  floatx4 acc[4][4];
  #pragma unroll
  for (int i = 0; i < 4; ++i)
    #pragma unroll
    for (int j = 0; j < 4; ++j) acc[i][j] = zero;

  auto stage = [&](int slot, int t) {
    const size_t ko = (size_t)t * 32;
    gload16(Ag0 + ko, &sA[slot][wb0]);
    gload16(Ag1 + ko, &sA[slot][wb1]);
    gload16(Bg0 + ko, &sB[slot][wb0]);
    gload16(Bg1 + ko, &sB[slot][wb1]);
  };

  const int nk = K >> 5;                 // >= 32 for all call sites
  stage(0, 0);
  stage(1, 1);

  int cur = 0;
  for (int t = 0; t < nk; ++t) {
    if (t + 1 < nk) {
      asm volatile("s_waitcnt vmcnt(4)" ::: "memory");   // step t landed
    } else {
      asm volatile("s_waitcnt vmcnt(0)" ::: "memory");   // final step
    }
    __builtin_amdgcn_s_barrier();        // step-t staging visible to all waves;
                                         // all waves done reading slot (t-1)%3
    if (t + 2 < nk) {                    // refill slot (t+2)%3 == (t-1)%3
      int nxt = cur + 2; if (nxt >= 3) nxt -= 3;
      stage(nxt, t + 2);
    }
    bf16x8 aF[4], bF[4];
    #pragma unroll
    for (int i = 0; i < 4; ++i) aF[i] = *(const bf16x8*)&sA[cur][aoff[i]];
    #pragma unroll
    for (int j = 0; j < 4; ++j) bF[j] = *(const bf16x8*)&sB[cur][boff[j]];
    #pragma unroll
    for (int i = 0; i < 4; ++i)
      #pragma unroll
      for (int j = 0; j < 4; ++j)
        acc[i][j] = MFMA16(aF[i], bF[j], acc[i][j]);
    cur = (cur == 2) ? 0 : cur + 1;
  }

  if (mode == 3) {                       // row bias, [bh][d][s] coalesced
    #pragma unroll
    for (int i = 0; i < 4; ++i) {
      #pragma unroll
      for (int r = 0; r < 4; ++r) {
        int gm = bm0 + wm + i * 16 + quad * 4 + r;   // (h,d)
        float bvr = bias[gm];
        int h = gm >> 6, d = gm & 63;
        #pragma unroll
        for (int j = 0; j < 4; ++j) {
          int gn = bn0 + wn + j * 16 + lrow;          // (b,s)
          int b = gn >> 11, s = gn & 2047;
          outB[((size_t)(b * 16 + h) * 64 + d) * 2048 + s] =
              (bf16)(acc[i][j][r] + bvr);
        }
      }
    }
    return;
  }

  float bvs[4];
  #pragma unroll
  for (int j = 0; j < 4; ++j) bvs[j] = bias[bn0 + wn + j * 16 + lrow];

  #pragma unroll
  for (int i = 0; i < 4; ++i) {
    #pragma unroll
    for (int j = 0; j < 4; ++j) {
      #pragma unroll
      for (int r = 0; r < 4; ++r) {
        int gm = bm0 + wm + i * 16 + quad * 4 + r;
        int gn = bn0 + wn + j * 16 + lrow;
        float v = (acc[i][j][r] + bvs[j]) * oscale;
        if (mode == 0) {
          outF[(size_t)gm * N + gn] = v;
        } else {
          // merged Q|K scatter: part 0 -> Qb, part 1 -> Kb (contiguous)
          int b = gm >> 11, s = gm & 2047;
          int part = gn >> 10, h = (gn >> 6) & 15, d = gn & 63;
          outB[(size_t)part * QBSZ +
               ((size_t)(b * 16 + h) * 2048 + s) * 64 + d] = (bf16)v;
        }
      }
    }
  }
}

// ---------------------------------------------------------------------------
// Pass 1 (log2 domain; Q pre-scaled by log2e): per-column exp2-sum over q>=c.
// NO running max: scores are bounded (|s| << 127 in log2 domain), so
// fp32 exp2 sums cannot overflow; C[c] = 3 + log2(sum) is mathematically
// identical to the max-tracked form.
// x = blockIdx.x directly (R5 xremap regressed: dispatch time is set by the
// long x=0 blocks, which need co-resident company for latency hiding).
// ---------------------------------------------------------------------------
__global__ __launch_bounds__(256) void attn_pass1(
    const bf16* __restrict__ Qb, const bf16* __restrict__ Kb,
    float* __restrict__ statC)
{
  const int bh = blockIdx.y;
  const int x = blockIdx.x;              // 0..15
  const int q0a = x * 64, q0b = (31 - x) * 64;
  const int tid = threadIdx.x;
  const int w = tid >> 6, lane = tid & 63, lrow = lane & 15, quad = lane >> 4;
  const bf16* Qh = Qb + (size_t)bh * S * Dh;
  const bf16* Kh = Kb + (size_t)bh * S * Dh;

  int cbase[8];
  #pragma unroll
  for (int cf = 0; cf < 8; ++cf)
    cbase[cf] = (cf < 4) ? (q0a + cf * 16) : (q0b + (cf - 4) * 16);

  bf16x8 kf[8][2];
  #pragma unroll
  for (int cf = 0; cf < 8; ++cf) {
    const bf16* kp = Kh + (size_t)(cbase[cf] + lrow) * Dh + quad * 8;
    kf[cf][0] = *(const bf16x8*)kp;
    kf[cf][1] = *(const bf16x8*)(kp + 32);
  }

  float rs[8];
  #pragma unroll
  for (int cf = 0; cf < 8; ++cf) rs[cf] = 0.f;

  const int qs = q0a + w * 16;
  const bf16* qp0 = Qh + (size_t)(qs + lrow) * Dh + quad * 8;
  bf16x8 a0 = *(const bf16x8*)qp0, a1 = *(const bf16x8*)(qp0 + 32);

  for (int q0 = qs; q0 < S; q0 += 64) {
    bf16x8 n0 = a0, n1 = a1;
    if (q0 + 64 < S) {
      const bf16* np = Qh + (size_t)(q0 + 64 + lrow) * Dh + quad * 8;
      n0 = *(const bf16x8*)np; n1 = *(const bf16x8*)(np + 32);
    }
    #pragma unroll
    for (int cf = 0; cf < 8; ++cf) {
      const int c0f = cbase[cf];
      if (c0f > q0 + 15) continue;          // frag fully masked (uniform)
      floatx4 sacc = {0.f, 0.f, 0.f, 0.f};
      sacc = MFMA16(a0, kf[cf][0], sacc);
      sacc = MFMA16(a1, kf[cf][1], sacc);
      float e0 = EXP2(sacc[0]), e1 = EXP2(sacc[1]);
      float e2 = EXP2(sacc[2]), e3 = EXP2(sacc[3]);
      if (q0 < c0f + 15) {                  // partially masked frag
        int c = c0f + lrow, qb = q0 + quad * 4;
        e0 = (qb + 0 >= c) ? e0 : 0.f;
        e1 = (qb + 1 >= c) ? e1 : 0.f;
        e2 = (qb + 2 >= c) ? e2 : 0.f;
        e3 = (qb + 3 >= c) ? e3 : 0.f;
      }
      rs[cf] += (e0 + e1) + (e2 + e3);
    }
    a0 = n0; a1 = n1;
  }

  #pragma unroll
  for (int cf = 0; cf < 8; ++cf) {
    rs[cf] += __shfl_xor(rs[cf], 16, 64);
    rs[cf] += __shfl_xor(rs[cf], 32, 64);
  }

  __shared__ float sms[4][128];
  if (quad == 0) {
    #pragma unroll
    for (int cf = 0; cf < 8; ++cf)
      sms[w][cf * 16 + lrow] = rs[cf];
  }
  __syncthreads();
  if (tid < 128) {
    float sum = (sms[0][tid] + sms[1][tid]) + (sms[2][tid] + sms[3][tid]);
    int col = (tid < 64) ? (q0a + tid) : (q0b + tid - 64);
    statC[(size_t)bh * S + col] = 3.0f + __log2f(sum);
  }
}

// ---------------------------------------------------------------------------
// Pass 2: out[q,:] = sum_{k<=q} exp2(s[q,k] - C[k]) * V[k,:]
// 256 threads / 4 waves, each wave owns TWO 16-row strips (mi=0,1) — the
// two independent strips give intra-wave ILP that hides MFMA/exp latency;
// 512-thread variants (R2: spilled; R3: lost co-residency, less ILP) were
// 301/111 µs vs this structure's 81.5 µs. Do not split strips across waves.
// x = blockIdx.x directly (R5 xremap regressed — see attn_pass1 note).
// S^T orientation: QK MFMA as (kf, qf) -> lane holds col=q, rows=4
// consecutive key-cols -> P written as ONE ds_write_b64 per frag.
// All LDS XOR-swizzled (128B rows) -> conflict-free.
// ---------------------------------------------------------------------------
__global__ __launch_bounds__(256) void attn_pass2(
    const bf16* __restrict__ Qb, const bf16* __restrict__ Kb,
    const bf16* __restrict__ Vt, const float* __restrict__ statC,
    bf16* __restrict__ AttOut)
{
  const int bh = blockIdx.y;
  const int x = blockIdx.x;              // 0..15
  const int q0a = x * 64, q0b = (31 - x) * 64;
  const int tid = threadIdx.x;
  const int w = tid >> 6, lane = tid & 63, lrow = lane & 15, quad = lane >> 4;
  const bf16* Qh = Qb + (size_t)bh * S * Dh;
  const bf16* Kh = Kb + (size_t)bh * S * Dh;
  const bf16* Vh = Vt + (size_t)bh * Dh * S;   // [d][s]
  const float* sth = statC + (size_t)bh * S;

  __shared__ bf16 sK[64 * 64];         // [s-row][d], swizzled 128B rows
  __shared__ bf16 sV[64 * 64];         // [d-row][s], swizzled
  __shared__ bf16 pbuf[4][32 * 64];    // per-wave P [q-row][c], swizzled

  const int r0m[2] = { q0a + w * 16, q0b + w * 16 };
  bf16x8 qf[2][2];
  #pragma unroll
  for (int mi = 0; mi < 2; ++mi) {
    const bf16* qp = Qh + (size_t)(r0m[mi] + lrow) * Dh + quad * 8;
    qf[mi][0] = *(const bf16x8*)qp;
    qf[mi][1] = *(const bf16x8*)(qp + 32);
  }

  floatx4 zero = {0.f, 0.f, 0.f, 0.f};
  floatx4 accO[2][4];
  #pragma unroll
  for (int mi = 0; mi < 2; ++mi)
    #pragma unroll
    for (int nf = 0; nf < 4; ++nf) accO[mi][nf] = zero;

  const int sr = tid >> 3;        // 0..31
  const int g  = tid & 7;         // 16B granule
  const int nT = 32 - x;          // tiles of 64 cols
  bf16* const pw = &pbuf[w][0];

  // prefetch tile 0 (K, V)
  bf16x8 kg0 = *(const bf16x8*)(Kh + (size_t)sr * Dh + g * 8);
  bf16x8 kg1 = *(const bf16x8*)(Kh + (size_t)(sr + 32) * Dh + g * 8);
  bf16x8 vg0 = *(const bf16x8*)(Vh + (size_t)sr * S + g * 8);
  bf16x8 vg1 = *(const bf16x8*)(Vh + (size_t)(sr + 32) * S + g * 8);

  for (int kt = 0; kt < nT; ++kt) {
    const int kc = kt * 64;
    __syncthreads();
    *(bf16x8*)&sK[swz(sr, g)]      = kg0;
    *(bf16x8*)&sK[swz(sr + 32, g)] = kg1;
    *(bf16x8*)&sV[swz(sr, g)]      = vg0;
    *(bf16x8*)&sV[swz(sr + 32, g)] = vg1;
    // C constants for this tile: quad-uniform float4 per cf (VMEM, L1-served)
    float4 c4[4];
    #pragma unroll
    for (int cf = 0; cf < 4; ++cf)
      c4[cf] = *(const float4*)&sth[kc + cf * 16 + quad * 4];
    __syncthreads();
    if (kt + 1 < nT) {                     // prefetch next K/V tile
      const int kn = kc + 64;
      kg0 = *(const bf16x8*)(Kh + (size_t)(kn + sr) * Dh + g * 8);
      kg1 = *(const bf16x8*)(Kh + (size_t)(kn + sr + 32) * Dh + g * 8);
      vg0 = *(const bf16x8*)(Vh + (size_t)sr * S + kn + g * 8);
      vg1 = *(const bf16x8*)(Vh + (size_t)(sr + 32) * S + kn + g * 8);
    }

    bool actH[2][2];
    #pragma unroll
    for (int mi = 0; mi < 2; ++mi) {
      actH[mi][0] = kc      <= r0m[mi] + 15;
      actH[mi][1] = kc + 32 <= r0m[mi] + 15;
    }

    // ---- S^T = K·Q^T + exp2 phase (cols=q, rows=c) ----
    #pragma unroll
    for (int cf = 0; cf < 4; ++cf) {
      const int hh = cf >> 1;
      if (!actH[0][hh] && !actH[1][hh]) continue;
      const int c0f = kc + cf * 16;
      const int cl = cf * 16;
      bf16x8 kf0 = *(const bf16x8*)&sK[swz(cl + lrow, quad)];
      bf16x8 kf1 = *(const bf16x8*)&sK[swz(cl + lrow, 4 + quad)];
      const float* cc = &c4[cf].x;                 // C[c0f+quad*4+r]
      const int crb = c0f + quad * 4;              // this lane's row base (c)
      #pragma unroll
      for (int mi = 0; mi < 2; ++mi) {
        if (!actH[mi][hh]) continue;
        const int r0 = r0m[mi];
        // dest: row mi*16+lrow, cols cf*16+quad*4..+3 -> one b64
        const int gq = cf * 2 + (quad >> 1);
        const int poff = (mi * 16 + lrow) * 64 +
                         ((gq ^ (lrow & 7)) << 3) + (quad & 1) * 4;
        bf16x4 pk;
        if (c0f > r0 + 15) {               // fully masked frag
          pk[0] = pk[1] = pk[2] = pk[3] = (bf16)0.f;
        } else {
          floatx4 sacc = zero;
          sacc = MFMA16(kf0, qf[mi][0], sacc);     // A=K -> row=c, col=q
          sacc = MFMA16(kf1, qf[mi][1], sacc);
          const bool fullf = (c0f + 15 <= r0);
          const int qlane = r0 + lrow;
          #pragma unroll
          for (int r = 0; r < 4; ++r) {
            float p = EXP2(sacc[r] - cc[r]);
            if (!fullf) p = (crb + r <= qlane) ? p : 0.f;
            pk[r] = (bf16)p;
          }
        }
        *(bf16x4*)(pw + poff) = pk;
      }
    }

    // ---- PV phase (two K=32 halves) ----
    #pragma unroll
    for (int hh = 0; hh < 2; ++hh) {
      if (!actH[0][hh] && !actH[1][hh]) continue;
      bf16x8 vf[4];
      #pragma unroll
      for (int nf = 0; nf < 4; ++nf)
        vf[nf] = *(const bf16x8*)&sV[swz(nf * 16 + lrow, hh * 4 + quad)];
      #pragma unroll
      for (int mi = 0; mi < 2; ++mi) {
        if (!actH[mi][hh]) continue;
        bf16x8 pf = *(const bf16x8*)(pw + swz(mi * 16 + lrow, hh * 4 + quad));
        #pragma unroll
        for (int nf = 0; nf < 4; ++nf)
          accO[mi][nf] = MFMA16(pf, vf[nf], accO[mi][nf]);
      }
    }
  }

  const int b = bh >> 4, h = bh & 15;
  #pragma unroll
  for (int mi = 0; mi < 2; ++mi) {
    #pragma unroll
    for (int nf = 0; nf < 4; ++nf) {
      #pragma unroll
      for (int r = 0; r < 4; ++r) {
        int qq = r0m[mi] + quad * 4 + r;
        int d = nf * 16 + lrow;
        AttOut[((size_t)(b * S + qq)) * DM + h * 64 + d] = (bf16)accO[mi][nf][r];
      }
    }
  }
}

// ---------------------------------------------------------------------------
extern "C" void kernel_launch(void* const* d_in, const int* in_sizes, int n_in,
                              void* d_out, int out_size, void* d_ws, size_t ws_size,
                              hipStream_t stream) {
  (void)in_sizes; (void)n_in; (void)out_size; (void)ws_size;
  const float* queries = (const float*)d_in[0];
  const float* keys    = (const float*)d_in[1];
  const float* values  = (const float*)d_in[2];
  const float* Wq_w = (const float*)d_in[3];  const float* Wq_b = (const float*)d_in[4];
  const float* Wk_w = (const float*)d_in[5];  const float* Wk_b = (const float*)d_in[6];
  const float* Wv_w = (const float*)d_in[7];  const float* Wv_b = (const float*)d_in[8];
  const float* Aq_w = (const float*)d_in[9];  const float* Aq_b = (const float*)d_in[10];
  const float* Bq_w = (const float*)d_in[11]; const float* Bq_b = (const float*)d_in[12];
  const float* Ak_w = (const float*)d_in[13]; const float* Ak_b = (const float*)d_in[14];
  const float* Bk_w = (const float*)d_in[15]; const float* Bk_b = (const float*)d_in[16];
  const float* Av_w = (const float*)d_in[17]; const float* Av_b = (const float*)d_in[18];
  const float* Bv_w = (const float*)d_in[19]; const float* Bv_b = (const float*)d_in[20];
  const float* Wo_w = (const float*)d_in[21]; const float* Wo_b = (const float*)d_in[22];
  float* out = (float*)d_out;

  char* ws = (char*)d_ws;
  size_t off = 0;
  auto alloc = [&](size_t bytes) -> void* {
    void* p = ws + off;
    off += (bytes + 255) & ~(size_t)255;
    return p;
  };
  bf16*  X_all  = (bf16*)alloc((size_t)8192 * 3072 * 2);
  bf16*  Qb     = (bf16*)alloc(QBSZ * 2 * 2);          // Qb || Kb contiguous
  bf16*  Kb     = Qb + QBSZ;
  bf16*  Vt     = (bf16*)alloc((size_t)64 * 64 * 2048 * 2);
  bf16*  AttOut = (bf16*)alloc((size_t)8192 * 1024 * 2);
  bf16*  WqkT   = (bf16*)alloc((size_t)2048 * 1024 * 2);  // WqT || WkT
  bf16*  WvT    = (bf16*)alloc((size_t)1024 * 2048 * 2);
  bf16*  WoT    = (bf16*)alloc((size_t)1024 * 1024 * 2);
  float* bqk    = (float*)alloc(2048 * 4);                // bq || bk
  float* bv     = (float*)alloc(1024 * 4);
  float* bo     = (float*)alloc(1024 * 4);
  float* statC  = (float*)alloc((size_t)64 * 2048 * 4);

  prep_convert<<<8192, 256, 0, stream>>>(queries, keys, values, X_all);
  fold_weights<<<dim3(32, 32), dim3(32, 8), 0, stream>>>(
      Wq_w, Aq_w, Bq_w, Wk_w, Ak_w, Bk_w, Wv_w, Av_w, Bv_w, Wo_w,
      WqkT, WqkT + (size_t)1024 * 1024, WvT, WoT);
  fold_bias<<<4, 256, 0, stream>>>(
      Wq_b, Aq_b, Bq_w, Bq_b, Wk_b, Ak_b, Bk_w, Bk_b,
      Wv_b, Av_b, Bv_w, Bv_b, Wo_b, bqk, bqk + 1024, bv, bo);

  // MERGED Q|K GEMM: M=8192, N=2048, K=1024 -> 1024 blocks
  gemm_bf16<<<dim3(16, 64), 256, 0, stream>>>(X_all, 3072, WqkT, 1024, bqk, 8192, 2048, 1024, 1.0f, nullptr, Qb, 1);
  // V computed TRANSPOSED: Vt = WvT @ X^T  (M=1024 rows=(h,d), N=8192=(b,s))
  gemm_bf16<<<dim3(64, 8), 256, 0, stream>>>(WvT, 2048, X_all + 1024, 3072, bv, 1024, 8192, 2048, 1.0f, nullptr, Vt, 3);

  attn_pass1<<<dim3(16, 64), 256, 0, stream>>>(Qb, Kb, statC);
  attn_pass2<<<dim3(16, 64), 256, 0, stream>>>(Qb, Kb, Vt, statC, AttOut);

  gemm_bf16<<<dim3(8, 64), 256, 0, stream>>>(AttOut, 1024, WoT, 1024, bo, 8192, 1024, 1024, 1.0f, out, nullptr, 0);
}

// Round 9
// 423.756 us; speedup vs baseline: 1.0822x; 1.0030x over previous
//
#include <hip/hip_runtime.h>
#include <math.h>
#include <stdint.h>

typedef __bf16 bf16;
typedef __bf16 bf16x8 __attribute__((ext_vector_type(8)));
typedef __bf16 bf16x4 __attribute__((ext_vector_type(4)));
typedef float  floatx4 __attribute__((ext_vector_type(4)));

#define MFMA16(a, b, c) __builtin_amdgcn_mfma_f32_16x16x32_bf16(a, b, c, 0, 0, 0)
#define EXP2(x) __builtin_amdgcn_exp2f(x)

static constexpr int S  = 2048;
static constexpr int DM = 1024;
static constexpr int Dh = 64;
static constexpr size_t QBSZ = (size_t)64 * 2048 * 64;   // elems in Qb (Kb follows)
#define NEGBIG (-1e30f)
#define LOG2E  1.44269504088896340736f

// async global->LDS, 16B per lane; LDS dest = wave-uniform base + lane*16
__device__ __forceinline__ void gload16(const void* g, void* l) {
  __builtin_amdgcn_global_load_lds(
      (const __attribute__((address_space(1))) void*)(uintptr_t)g,
      (__attribute__((address_space(3))) void*)(uintptr_t)l,
      16, 0, 0);
}

// XOR-swizzled LDS offset for 64-elem (128B) rows, granule g (16B) xor'd by
// row&7 (attn tiles).
__device__ __forceinline__ int swz(int row, int g) {
  return row * 64 + ((g ^ (row & 7)) << 3);
}

// ---------------------------------------------------------------------------
// Pack queries|values|keys into one bf16 [8192][3072] buffer (X_all).
// ---------------------------------------------------------------------------
__global__ __launch_bounds__(256) void prep_convert(
    const float* __restrict__ q, const float* __restrict__ k,
    const float* __restrict__ v, bf16* __restrict__ X)
{
  int s = blockIdx.x;
  int c = threadIdx.x * 4;
  size_t src = (size_t)s * DM + c;
  float4 qv = *(const float4*)(q + src);
  float4 vv = *(const float4*)(v + src);
  float4 kv = *(const float4*)(k + src);
  size_t dst = (size_t)s * (3 * DM);
  bf16x4 t;
  t[0] = (bf16)qv.x; t[1] = (bf16)qv.y; t[2] = (bf16)qv.z; t[3] = (bf16)qv.w;
  *(bf16x4*)(X + dst + c) = t;
  t[0] = (bf16)vv.x; t[1] = (bf16)vv.y; t[2] = (bf16)vv.z; t[3] = (bf16)vv.w;
  *(bf16x4*)(X + dst + DM + c) = t;
  t[0] = (bf16)kv.x; t[1] = (bf16)kv.y; t[2] = (bf16)kv.z; t[3] = (bf16)kv.w;
  *(bf16x4*)(X + dst + 2 * DM + c) = t;
}

// ---------------------------------------------------------------------------
// Fold LoRA into effective weights (transposed bf16 for GEMM B-operand).
// Wq gets LOG2E folded in (so the merged Q|K GEMM uses one oscale=1).
// ---------------------------------------------------------------------------
__global__ __launch_bounds__(256) void fold_weights(
    const float* __restrict__ Wq, const float* __restrict__ Aq, const float* __restrict__ Bq,
    const float* __restrict__ Wk, const float* __restrict__ Ak, const float* __restrict__ Bk,
    const float* __restrict__ Wv, const float* __restrict__ Av, const float* __restrict__ Bv,
    const float* __restrict__ Wo,
    bf16* __restrict__ WqT, bf16* __restrict__ WkT,
    bf16* __restrict__ WvT, bf16* __restrict__ WoT)
{
  __shared__ float tile[32][33];
  const int tx = threadIdx.x, ty = threadIdx.y;  // block (32, 8)
  const int n0 = blockIdx.x * 32, k0 = blockIdx.y * 32;
  for (int mi = 0; mi < 5; ++mi) {
    #pragma unroll
    for (int i = 0; i < 4; ++i) {
      int k = k0 + ty + i * 8, n = n0 + tx;
      float val = 0.f;
      if (mi == 0) {
        val = Wq[(size_t)k * DM + n];
        #pragma unroll
        for (int r = 0; r < 8; ++r) val += Aq[k * 8 + r] * Bq[(size_t)r * DM + n];
        val *= LOG2E;
      } else if (mi == 1) {
        val = Wk[(size_t)k * DM + n];
        #pragma unroll
        for (int r = 0; r < 8; ++r) val += Ak[k * 8 + r] * Bk[(size_t)r * DM + n];
      } else if (mi == 2) {
        val = Wv[(size_t)k * DM + n];
      } else if (mi == 3) {
        #pragma unroll
        for (int r = 0; r < 8; ++r) val += Av[k * 8 + r] * Bv[(size_t)r * DM + n];
      } else {
        val = Wo[(size_t)k * DM + n];
      }
      tile[ty + i * 8][tx] = val;
    }
    __syncthreads();
    #pragma unroll
    for (int i = 0; i < 4; ++i) {
      int n = n0 + ty + i * 8, k = k0 + tx;
      float val = tile[tx][ty + i * 8];
      if (mi == 0)      WqT[(size_t)n * DM + k] = (bf16)val;
      else if (mi == 1) WkT[(size_t)n * DM + k] = (bf16)val;
      else if (mi == 2) WvT[(size_t)n * 2048 + k] = (bf16)val;
      else if (mi == 3) WvT[(size_t)n * 2048 + 1024 + k] = (bf16)val;
      else              WoT[(size_t)n * DM + k] = (bf16)val;
    }
    __syncthreads();
  }
}

__global__ __launch_bounds__(256) void fold_bias(
    const float* __restrict__ Wqb, const float* __restrict__ Aqb,
    const float* __restrict__ BqW, const float* __restrict__ Bqb,
    const float* __restrict__ Wkb, const float* __restrict__ Akb,
    const float* __restrict__ BkW, const float* __restrict__ Bkb,
    const float* __restrict__ Wvb, const float* __restrict__ Avb,
    const float* __restrict__ BvW, const float* __restrict__ Bvb,
    const float* __restrict__ Wob,
    float* __restrict__ bq, float* __restrict__ bk,
    float* __restrict__ bv, float* __restrict__ bo)
{
  int n = blockIdx.x * 256 + threadIdx.x;
  float aq = Wqb[n] + Bqb[n];
  float ak = Wkb[n] + Bkb[n];
  float av = Wvb[n] + Bvb[n];
  #pragma unroll
  for (int r = 0; r < 8; ++r) {
    aq += Aqb[r] * BqW[(size_t)r * DM + n];
    ak += Akb[r] * BkW[(size_t)r * DM + n];
    av += Avb[r] * BvW[(size_t)r * DM + n];
  }
  bq[n] = aq * LOG2E;            // LOG2E folded (merged Q|K GEMM, oscale=1)
  bk[n] = ak; bv[n] = av; bo[n] = Wob[n];
}

// ---------------------------------------------------------------------------
// MERGED QK+V GEMM: one 1536-block dispatch.
//   blocks [0,1024):   QK  M=8192 N=2048 K=1024 (A=X cols by part, BT=WqkT)
//   blocks [1024,1536): V   M=1024 N=8192 K=2048 (A=WvT, BT=X values-cols)
// m97 shape: 256 thr / 4 waves, 64x64 per wave, 16 MFMA/K-step.
// 2-slot LDS double buffer (32 KB) + __launch_bounds__(256,4) (VGPR<=128)
// -> 4 blocks/CU co-resident (vs 3 with the 48KB ring): trades pipeline
// depth for TLP, which m114-style wave overlap favors. V blocks backfill
// as QK blocks retire (no inter-dispatch drain; V no longer stuck at 2/CU).
// ---------------------------------------------------------------------------
__global__ __launch_bounds__(256, 4) void gemm_qkv(
    const bf16* __restrict__ X, const bf16* __restrict__ WqkT,
    const bf16* __restrict__ WvT,
    const float* __restrict__ bqk, const float* __restrict__ bv,
    bf16* __restrict__ Qb, bf16* __restrict__ Vt)
{
  __shared__ bf16 sA[2][128 * 32];
  __shared__ bf16 sB[2][128 * 32];
  const int tid = threadIdx.x;
  const int w = tid >> 6, lane = tid & 63, lrow = lane & 15, quad = lane >> 4;
  const int wm = (w >> 1) * 64, wn = (w & 1) * 64;

  int id = blockIdx.x;
  const bf16 *A, *BT;
  const float* bias;
  bf16* outB;
  int lda, ldb, K, bm0, bn0, mode;
  if (id < 1024) {                       // QK part
    int bx = id & 15, by = id >> 4;
    bm0 = by * 128; bn0 = bx * 128;
    A = X + (size_t)(bn0 >> 10) * 2048;  // upper n-half reads keys cols
    lda = 3072; BT = WqkT; ldb = 1024; K = 1024;
    bias = bqk; outB = Qb; mode = 1;
  } else {                               // V part (computed transposed)
    id -= 1024;
    int bx = id & 63, by = id >> 6;
    bm0 = by * 128; bn0 = bx * 128;
    A = WvT; lda = 2048;
    BT = X + 1024; ldb = 3072; K = 2048;
    bias = bv; outB = Vt; mode = 3;
  }

  // staging: thread t loads granules t and t+256 (rows r0 and r0+64).
  const int r0 = tid >> 2;                       // 0..63
  const int c0 = (tid & 3) ^ ((r0 >> 1) & 3);    // pre-swizzled src granule
  const bf16* Ag0 = A  + (size_t)(bm0 + r0) * lda + c0 * 8;
  const bf16* Ag1 = A  + (size_t)(bm0 + r0 + 64) * lda + c0 * 8;
  const bf16* Bg0 = BT + (size_t)(bn0 + r0) * ldb + c0 * 8;
  const bf16* Bg1 = BT + (size_t)(bn0 + r0 + 64) * ldb + c0 * 8;
  const int wb0 = w * 512;
  const int wb1 = 2048 + w * 512;

  int aoff[4], boff[4];
  #pragma unroll
  for (int i = 0; i < 4; ++i) {
    int ra = wm + i * 16 + lrow;
    aoff[i] = ra * 32 + ((quad ^ ((ra >> 1) & 3)) << 3);
    int rb = wn + i * 16 + lrow;
    boff[i] = rb * 32 + ((quad ^ ((rb >> 1) & 3)) << 3);
  }

  floatx4 zero = {0.f, 0.f, 0.f, 0.f};
  floatx4 acc[4][4];
  #pragma unroll
  for (int i = 0; i < 4; ++i)
    #pragma unroll
    for (int j = 0; j < 4; ++j) acc[i][j] = zero;

  auto stage = [&](int slot, int t) {
    const size_t ko = (size_t)t * 32;
    gload16(Ag0 + ko, &sA[slot][wb0]);
    gload16(Ag1 + ko, &sA[slot][wb1]);
    gload16(Bg0 + ko, &sB[slot][wb0]);
    gload16(Bg1 + ko, &sB[slot][wb1]);
  };

  const int nk = K >> 5;
  stage(0, 0);

  for (int t = 0; t < nk; ++t) {
    const int cur = t & 1;
    __syncthreads();                     // drains slot[cur] staging; proves all
                                         // waves done reading slot[cur^1]
    if (t + 1 < nk) stage(cur ^ 1, t + 1);   // in flight across compute(t)
    bf16x8 aF[4], bF[4];
    #pragma unroll
    for (int i = 0; i < 4; ++i) aF[i] = *(const bf16x8*)&sA[cur][aoff[i]];
    #pragma unroll
    for (int j = 0; j < 4; ++j) bF[j] = *(const bf16x8*)&sB[cur][boff[j]];
    #pragma unroll
    for (int i = 0; i < 4; ++i)
      #pragma unroll
      for (int j = 0; j < 4; ++j)
        acc[i][j] = MFMA16(aF[i], bF[j], acc[i][j]);
  }

  if (mode == 3) {                       // row bias, [bh][d][s] coalesced
    #pragma unroll
    for (int i = 0; i < 4; ++i) {
      #pragma unroll
      for (int r = 0; r < 4; ++r) {
        int gm = bm0 + wm + i * 16 + quad * 4 + r;   // (h,d)
        float bvr = bias[gm];
        int h = gm >> 6, d = gm & 63;
        #pragma unroll
        for (int j = 0; j < 4; ++j) {
          int gn = bn0 + wn + j * 16 + lrow;          // (b,s)
          int b = gn >> 11, s = gn & 2047;
          outB[((size_t)(b * 16 + h) * 64 + d) * 2048 + s] =
              (bf16)(acc[i][j][r] + bvr);
        }
      }
    }
    return;
  }

  float bvs[4];
  #pragma unroll
  for (int j = 0; j < 4; ++j) bvs[j] = bias[bn0 + wn + j * 16 + lrow];

  #pragma unroll
  for (int i = 0; i < 4; ++i) {
    #pragma unroll
    for (int j = 0; j < 4; ++j) {
      #pragma unroll
      for (int r = 0; r < 4; ++r) {
        int gm = bm0 + wm + i * 16 + quad * 4 + r;
        int gn = bn0 + wn + j * 16 + lrow;
        float v = acc[i][j][r] + bvs[j];
        // merged Q|K scatter: part 0 -> Qb, part 1 -> Kb (contiguous)
        int b = gm >> 11, s = gm & 2047;
        int part = gn >> 10, h = (gn >> 6) & 15, d = gn & 63;
        outB[(size_t)part * QBSZ +
             ((size_t)(b * 16 + h) * 2048 + s) * 64 + d] = (bf16)v;
      }
    }
  }
}

// ---------------------------------------------------------------------------
// m97-shape 128x128 bf16 MFMA GEMM (Wo only now): 256 thr / 4 waves, 64x64
// per wave, 16 MFMA/K-step; T4 3-slot ring (48 KB), counted vmcnt(4).
// mode 0: fp32 [M][N] (+col bias)
// ---------------------------------------------------------------------------
__global__ __launch_bounds__(256) void gemm_bf16(
    const bf16* __restrict__ A, int lda,
    const bf16* __restrict__ BT, int ldb,
    const float* __restrict__ bias,
    int M, int N, int K, float oscale,
    float* __restrict__ outF, bf16* __restrict__ outB, int mode)
{
  __shared__ bf16 sA[3][128 * 32];
  __shared__ bf16 sB[3][128 * 32];
  const int tid = threadIdx.x;
  const int bm0 = blockIdx.y * 128, bn0 = blockIdx.x * 128;
  const int w = tid >> 6, lane = tid & 63, lrow = lane & 15, quad = lane >> 4;
  const int wm = (w >> 1) * 64, wn = (w & 1) * 64;

  const int r0 = tid >> 2;                       // 0..63
  const int c0 = (tid & 3) ^ ((r0 >> 1) & 3);    // pre-swizzled src granule
  const bf16* Ag0 = A + (size_t)(bm0 + r0) * lda + c0 * 8;
  const bf16* Ag1 = A + (size_t)(bm0 + r0 + 64) * lda + c0 * 8;
  const bf16* Bg0 = BT + (size_t)(bn0 + r0) * ldb + c0 * 8;
  const bf16* Bg1 = BT + (size_t)(bn0 + r0 + 64) * ldb + c0 * 8;
  const int wb0 = w * 512;
  const int wb1 = 2048 + w * 512;

  int aoff[4], boff[4];
  #pragma unroll
  for (int i = 0; i < 4; ++i) {
    int ra = wm + i * 16 + lrow;
    aoff[i] = ra * 32 + ((quad ^ ((ra >> 1) & 3)) << 3);
    int rb = wn + i * 16 + lrow;
    boff[i] = rb * 32 + ((quad ^ ((rb >> 1) & 3)) << 3);
  }

  floatx4 zero = {0.f, 0.f, 0.f, 0.f};
  floatx4 acc[4][4];
  #pragma unroll
  for (int i = 0; i < 4; ++i)
    #pragma unroll
    for (int j = 0; j < 4; ++j) acc[i][j] = zero;

  auto stage = [&](int slot, int t) {
    const size_t ko = (size_t)t * 32;
    gload16(Ag0 + ko, &sA[slot][wb0]);
    gload16(Ag1 + ko, &sA[slot][wb1]);
    gload16(Bg0 + ko, &sB[slot][wb0]);
    gload16(Bg1 + ko, &sB[slot][wb1]);
  };

  const int nk = K >> 5;
  stage(0, 0);
  stage(1, 1);

  int cur = 0;
  for (int t = 0; t < nk; ++t) {
    if (t + 1 < nk) {
      asm volatile("s_waitcnt vmcnt(4)" ::: "memory");
    } else {
      asm volatile("s_waitcnt vmcnt(0)" ::: "memory");
    }
    __builtin_amdgcn_s_barrier();
    if (t + 2 < nk) {
      int nxt = cur + 2; if (nxt >= 3) nxt -= 3;
      stage(nxt, t + 2);
    }
    bf16x8 aF[4], bF[4];
    #pragma unroll
    for (int i = 0; i < 4; ++i) aF[i] = *(const bf16x8*)&sA[cur][aoff[i]];
    #pragma unroll
    for (int j = 0; j < 4; ++j) bF[j] = *(const bf16x8*)&sB[cur][boff[j]];
    #pragma unroll
    for (int i = 0; i < 4; ++i)
      #pragma unroll
      for (int j = 0; j < 4; ++j)
        acc[i][j] = MFMA16(aF[i], bF[j], acc[i][j]);
    cur = (cur == 2) ? 0 : cur + 1;
  }

  float bvs[4];
  #pragma unroll
  for (int j = 0; j < 4; ++j) bvs[j] = bias[bn0 + wn + j * 16 + lrow];

  #pragma unroll
  for (int i = 0; i < 4; ++i) {
    #pragma unroll
    for (int j = 0; j < 4; ++j) {
      #pragma unroll
      for (int r = 0; r < 4; ++r) {
        int gm = bm0 + wm + i * 16 + quad * 4 + r;
        int gn = bn0 + wn + j * 16 + lrow;
        outF[(size_t)gm * N + gn] = (acc[i][j][r] + bvs[j]) * oscale;
      }
    }
  }
}

// ---------------------------------------------------------------------------
// Pass 1 (log2 domain; Q pre-scaled by log2e): per-column exp2-sum over q>=c.
// NO running max: scores bounded (|s| << 127 in log2 domain) -> fp32 exp2
// sums can't overflow; C[c] = 3 + log2(sum) identical to max-tracked form.
// x = blockIdx.x directly (R5 xremap regressed).
// ---------------------------------------------------------------------------
__global__ __launch_bounds__(256) void attn_pass1(
    const bf16* __restrict__ Qb, const bf16* __restrict__ Kb,
    float* __restrict__ statC)
{
  const int bh = blockIdx.y;
  const int x = blockIdx.x;              // 0..15
  const int q0a = x * 64, q0b = (31 - x) * 64;
  const int tid = threadIdx.x;
  const int w = tid >> 6, lane = tid & 63, lrow = lane & 15, quad = lane >> 4;
  const bf16* Qh = Qb + (size_t)bh * S * Dh;
  const bf16* Kh = Kb + (size_t)bh * S * Dh;

  int cbase[8];
  #pragma unroll
  for (int cf = 0; cf < 8; ++cf)
    cbase[cf] = (cf < 4) ? (q0a + cf * 16) : (q0b + (cf - 4) * 16);

  bf16x8 kf[8][2];
  #pragma unroll
  for (int cf = 0; cf < 8; ++cf) {
    const bf16* kp = Kh + (size_t)(cbase[cf] + lrow) * Dh + quad * 8;
    kf[cf][0] = *(const bf16x8*)kp;
    kf[cf][1] = *(const bf16x8*)(kp + 32);
  }

  float rs[8];
  #pragma unroll
  for (int cf = 0; cf < 8; ++cf) rs[cf] = 0.f;

  const int qs = q0a + w * 16;
  const bf16* qp0 = Qh + (size_t)(qs + lrow) * Dh + quad * 8;
  bf16x8 a0 = *(const bf16x8*)qp0, a1 = *(const bf16x8*)(qp0 + 32);

  for (int q0 = qs; q0 < S; q0 += 64) {
    bf16x8 n0 = a0, n1 = a1;
    if (q0 + 64 < S) {
      const bf16* np = Qh + (size_t)(q0 + 64 + lrow) * Dh + quad * 8;
      n0 = *(const bf16x8*)np; n1 = *(const bf16x8*)(np + 32);
    }
    #pragma unroll
    for (int cf = 0; cf < 8; ++cf) {
      const int c0f = cbase[cf];
      if (c0f > q0 + 15) continue;          // frag fully masked (uniform)
      floatx4 sacc = {0.f, 0.f, 0.f, 0.f};
      sacc = MFMA16(a0, kf[cf][0], sacc);
      sacc = MFMA16(a1, kf[cf][1], sacc);
      float e0 = EXP2(sacc[0]), e1 = EXP2(sacc[1]);
      float e2 = EXP2(sacc[2]), e3 = EXP2(sacc[3]);
      if (q0 < c0f + 15) {                  // partially masked frag
        int c = c0f + lrow, qb = q0 + quad * 4;
        e0 = (qb + 0 >= c) ? e0 : 0.f;
        e1 = (qb + 1 >= c) ? e1 : 0.f;
        e2 = (qb + 2 >= c) ? e2 : 0.f;
        e3 = (qb + 3 >= c) ? e3 : 0.f;
      }
      rs[cf] += (e0 + e1) + (e2 + e3);
    }
    a0 = n0; a1 = n1;
  }

  #pragma unroll
  for (int cf = 0; cf < 8; ++cf) {
    rs[cf] += __shfl_xor(rs[cf], 16, 64);
    rs[cf] += __shfl_xor(rs[cf], 32, 64);
  }

  __shared__ float sms[4][128];
  if (quad == 0) {
    #pragma unroll
    for (int cf = 0; cf < 8; ++cf)
      sms[w][cf * 16 + lrow] = rs[cf];
  }
  __syncthreads();
  if (tid < 128) {
    float sum = (sms[0][tid] + sms[1][tid]) + (sms[2][tid] + sms[3][tid]);
    int col = (tid < 64) ? (q0a + tid) : (q0b + tid - 64);
    statC[(size_t)bh * S + col] = 3.0f + __log2f(sum);
  }
}

// ---------------------------------------------------------------------------
// Pass 2: out[q,:] = sum_{k<=q} exp2(s[q,k] - C[k]) * V[k,:]
// 256 threads / 4 waves, each wave owns TWO 16-row strips (mi=0,1) — the
// two independent strips give intra-wave ILP that hides MFMA/exp latency;
// 512-thread variants (R2: spilled; R3: lost co-residency, less ILP) were
// 301/111 µs vs this structure's 81.5 µs. Do not split strips across waves.
// x = blockIdx.x directly (R5 xremap regressed).
// S^T orientation: QK MFMA as (kf, qf) -> lane holds col=q, rows=4
// consecutive key-cols -> P written as ONE ds_write_b64 per frag.
// All LDS XOR-swizzled (128B rows) -> conflict-free.
// ---------------------------------------------------------------------------
__global__ __launch_bounds__(256) void attn_pass2(
    const bf16* __restrict__ Qb, const bf16* __restrict__ Kb,
    const bf16* __restrict__ Vt, const float* __restrict__ statC,
    bf16* __restrict__ AttOut)
{
  const int bh = blockIdx.y;
  const int x = blockIdx.x;              // 0..15
  const int q0a = x * 64, q0b = (31 - x) * 64;
  const int tid = threadIdx.x;
  const int w = tid >> 6, lane = tid & 63, lrow = lane & 15, quad = lane >> 4;
  const bf16* Qh = Qb + (size_t)bh * S * Dh;
  const bf16* Kh = Kb + (size_t)bh * S * Dh;
  const bf16* Vh = Vt + (size_t)bh * Dh * S;   // [d][s]
  const float* sth = statC + (size_t)bh * S;

  __shared__ bf16 sK[64 * 64];         // [s-row][d], swizzled 128B rows
  __shared__ bf16 sV[64 * 64];         // [d-row][s], swizzled
  __shared__ bf16 pbuf[4][32 * 64];    // per-wave P [q-row][c], swizzled

  const int r0m[2] = { q0a + w * 16, q0b + w * 16 };
  bf16x8 qf[2][2];
  #pragma unroll
  for (int mi = 0; mi < 2; ++mi) {
    const bf16* qp = Qh + (size_t)(r0m[mi] + lrow) * Dh + quad * 8;
    qf[mi][0] = *(const bf16x8*)qp;
    qf[mi][1] = *(const bf16x8*)(qp + 32);
  }

  floatx4 zero = {0.f, 0.f, 0.f, 0.f};
  floatx4 accO[2][4];
  #pragma unroll
  for (int mi = 0; mi < 2; ++mi)
    #pragma unroll
    for (int nf = 0; nf < 4; ++nf) accO[mi][nf] = zero;

  const int sr = tid >> 3;        // 0..31
  const int g  = tid & 7;         // 16B granule
  const int nT = 32 - x;          // tiles of 64 cols
  bf16* const pw = &pbuf[w][0];

  // prefetch tile 0 (K, V)
  bf16x8 kg0 = *(const bf16x8*)(Kh + (size_t)sr * Dh + g * 8);
  bf16x8 kg1 = *(const bf16x8*)(Kh + (size_t)(sr + 32) * Dh + g * 8);
  bf16x8 vg0 = *(const bf16x8*)(Vh + (size_t)sr * S + g * 8);
  bf16x8 vg1 = *(const bf16x8*)(Vh + (size_t)(sr + 32) * S + g * 8);

  for (int kt = 0; kt < nT; ++kt) {
    const int kc = kt * 64;
    __syncthreads();
    *(bf16x8*)&sK[swz(sr, g)]      = kg0;
    *(bf16x8*)&sK[swz(sr + 32, g)] = kg1;
    *(bf16x8*)&sV[swz(sr, g)]      = vg0;
    *(bf16x8*)&sV[swz(sr + 32, g)] = vg1;
    // C constants for this tile: quad-uniform float4 per cf (VMEM, L1-served)
    float4 c4[4];
    #pragma unroll
    for (int cf = 0; cf < 4; ++cf)
      c4[cf] = *(const float4*)&sth[kc + cf * 16 + quad * 4];
    __syncthreads();
    if (kt + 1 < nT) {                     // prefetch next K/V tile
      const int kn = kc + 64;
      kg0 = *(const bf16x8*)(Kh + (size_t)(kn + sr) * Dh + g * 8);
      kg1 = *(const bf16x8*)(Kh + (size_t)(kn + sr + 32) * Dh + g * 8);
      vg0 = *(const bf16x8*)(Vh + (size_t)sr * S + kn + g * 8);
      vg1 = *(const bf16x8*)(Vh + (size_t)(sr + 32) * S + kn + g * 8);
    }

    bool actH[2][2];
    #pragma unroll
    for (int mi = 0; mi < 2; ++mi) {
      actH[mi][0] = kc      <= r0m[mi] + 15;
      actH[mi][1] = kc + 32 <= r0m[mi] + 15;
    }

    // ---- S^T = K·Q^T + exp2 phase (cols=q, rows=c) ----
    #pragma unroll
    for (int cf = 0; cf < 4; ++cf) {
      const int hh = cf >> 1;
      if (!actH[0][hh] && !actH[1][hh]) continue;
      const int c0f = kc + cf * 16;
      const int cl = cf * 16;
      bf16x8 kf0 = *(const bf16x8*)&sK[swz(cl + lrow, quad)];
      bf16x8 kf1 = *(const bf16x8*)&sK[swz(cl + lrow, 4 + quad)];
      const float* cc = &c4[cf].x;                 // C[c0f+quad*4+r]
      const int crb = c0f + quad * 4;              // this lane's row base (c)
      #pragma unroll
      for (int mi = 0; mi < 2; ++mi) {
        if (!actH[mi][hh]) continue;
        const int r0 = r0m[mi];
        // dest: row mi*16+lrow, cols cf*16+quad*4..+3 -> one b64
        const int gq = cf * 2 + (quad >> 1);
        const int poff = (mi * 16 + lrow) * 64 +
                         ((gq ^ (lrow & 7)) << 3) + (quad & 1) * 4;
        bf16x4 pk;
        if (c0f > r0 + 15) {               // fully masked frag
          pk[0] = pk[1] = pk[2] = pk[3] = (bf16)0.f;
        } else {
          floatx4 sacc = zero;
          sacc = MFMA16(kf0, qf[mi][0], sacc);     // A=K -> row=c, col=q
          sacc = MFMA16(kf1, qf[mi][1], sacc);
          const bool fullf = (c0f + 15 <= r0);
          const int qlane = r0 + lrow;
          #pragma unroll
          for (int r = 0; r < 4; ++r) {
            float p = EXP2(sacc[r] - cc[r]);
            if (!fullf) p = (crb + r <= qlane) ? p : 0.f;
            pk[r] = (bf16)p;
          }
        }
        *(bf16x4*)(pw + poff) = pk;
      }
    }

    // ---- PV phase (two K=32 halves) ----
    #pragma unroll
    for (int hh = 0; hh < 2; ++hh) {
      if (!actH[0][hh] && !actH[1][hh]) continue;
      bf16x8 vf[4];
      #pragma unroll
      for (int nf = 0; nf < 4; ++nf)
        vf[nf] = *(const bf16x8*)&sV[swz(nf * 16 + lrow, hh * 4 + quad)];
      #pragma unroll
      for (int mi = 0; mi < 2; ++mi) {
        if (!actH[mi][hh]) continue;
        bf16x8 pf = *(const bf16x8*)(pw + swz(mi * 16 + lrow, hh * 4 + quad));
        #pragma unroll
        for (int nf = 0; nf < 4; ++nf)
          accO[mi][nf] = MFMA16(pf, vf[nf], accO[mi][nf]);
      }
    }
  }

  const int b = bh >> 4, h = bh & 15;
  #pragma unroll
  for (int mi = 0; mi < 2; ++mi) {
    #pragma unroll
    for (int nf = 0; nf < 4; ++nf) {
      #pragma unroll
      for (int r = 0; r < 4; ++r) {
        int qq = r0m[mi] + quad * 4 + r;
        int d = nf * 16 + lrow;
        AttOut[((size_t)(b * S + qq)) * DM + h * 64 + d] = (bf16)accO[mi][nf][r];
      }
    }
  }
}

// ---------------------------------------------------------------------------
extern "C" void kernel_launch(void* const* d_in, const int* in_sizes, int n_in,
                              void* d_out, int out_size, void* d_ws, size_t ws_size,
                              hipStream_t stream) {
  (void)in_sizes; (void)n_in; (void)out_size; (void)ws_size;
  const float* queries = (const float*)d_in[0];
  const float* keys    = (const float*)d_in[1];
  const float* values  = (const float*)d_in[2];
  const float* Wq_w = (const float*)d_in[3];  const float* Wq_b = (const float*)d_in[4];
  const float* Wk_w = (const float*)d_in[5];  const float* Wk_b = (const float*)d_in[6];
  const float* Wv_w = (const float*)d_in[7];  const float* Wv_b = (const float*)d_in[8];
  const float* Aq_w = (const float*)d_in[9];  const float* Aq_b = (const float*)d_in[10];
  const float* Bq_w = (const float*)d_in[11]; const float* Bq_b = (const float*)d_in[12];
  const float* Ak_w = (const float*)d_in[13]; const float* Ak_b = (const float*)d_in[14];
  const float* Bk_w = (const float*)d_in[15]; const float* Bk_b = (const float*)d_in[16];
  const float* Av_w = (const float*)d_in[17]; const float* Av_b = (const float*)d_in[18];
  const float* Bv_w = (const float*)d_in[19]; const float* Bv_b = (const float*)d_in[20];
  const float* Wo_w = (const float*)d_in[21]; const float* Wo_b = (const float*)d_in[22];
  float* out = (float*)d_out;

  char* ws = (char*)d_ws;
  size_t off = 0;
  auto alloc = [&](size_t bytes) -> void* {
    void* p = ws + off;
    off += (bytes + 255) & ~(size_t)255;
    return p;
  };
  bf16*  X_all  = (bf16*)alloc((size_t)8192 * 3072 * 2);
  bf16*  Qb     = (bf16*)alloc(QBSZ * 2 * 2);          // Qb || Kb contiguous
  bf16*  Kb     = Qb + QBSZ;
  bf16*  Vt     = (bf16*)alloc((size_t)64 * 64 * 2048 * 2);
  bf16*  AttOut = (bf16*)alloc((size_t)8192 * 1024 * 2);
  bf16*  WqkT   = (bf16*)alloc((size_t)2048 * 1024 * 2);  // WqT || WkT
  bf16*  WvT    = (bf16*)alloc((size_t)1024 * 2048 * 2);
  bf16*  WoT    = (bf16*)alloc((size_t)1024 * 1024 * 2);
  float* bqk    = (float*)alloc(2048 * 4);                // bq || bk
  float* bv     = (float*)alloc(1024 * 4);
  float* bo     = (float*)alloc(1024 * 4);
  float* statC  = (float*)alloc((size_t)64 * 2048 * 4);

  prep_convert<<<8192, 256, 0, stream>>>(queries, keys, values, X_all);
  fold_weights<<<dim3(32, 32), dim3(32, 8), 0, stream>>>(
      Wq_w, Aq_w, Bq_w, Wk_w, Ak_w, Bk_w, Wv_w, Av_w, Bv_w, Wo_w,
      WqkT, WqkT + (size_t)1024 * 1024, WvT, WoT);
  fold_bias<<<4, 256, 0, stream>>>(
      Wq_b, Aq_b, Bq_w, Bq_b, Wk_b, Ak_b, Bk_w, Bk_b,
      Wv_b, Av_b, Bv_w, Bv_b, Wo_b, bqk, bqk + 1024, bv, bo);

  // MERGED QK+V GEMM: 1536 blocks (1024 QK + 512 V), 4 blocks/CU capacity
  gemm_qkv<<<1536, 256, 0, stream>>>(X_all, WqkT, WvT, bqk, bv, Qb, Vt);

  attn_pass1<<<dim3(16, 64), 256, 0, stream>>>(Qb, Kb, statC);
  attn_pass2<<<dim3(16, 64), 256, 0, stream>>>(Qb, Kb, Vt, statC, AttOut);

  gemm_bf16<<<dim3(8, 64), 256, 0, stream>>>(AttOut, 1024, WoT, 1024, bo, 8192, 1024, 1024, 1.0f, out, nullptr, 0);
}